// Round 4
// baseline (933.674 us; speedup 1.0000x reference)
//
#include <hip/hip_runtime.h>

#define DIM 64
#define EPW 32   // edges per wave in final_kernel

__device__ __forceinline__ float bf2f(unsigned short u) {
    union { unsigned int i; float f; } v; v.i = ((unsigned int)u) << 16; return v.f;
}
__device__ __forceinline__ unsigned short f2bf(float f) {
    union { float f; unsigned int i; } v; v.f = f;
    unsigned int r = v.i + 0x7fff + ((v.i >> 16) & 1);   // RNE (no NaN inputs here)
    return (unsigned short)(r >> 16);
}
__device__ __forceinline__ float4 u2f4(ushort4 u) {
    float4 f; f.x = bf2f(u.x); f.y = bf2f(u.y); f.z = bf2f(u.z); f.w = bf2f(u.w);
    return f;
}
__device__ __forceinline__ ushort4 f2u4(float4 f) {
    ushort4 u; u.x = f2bf(f.x); u.y = f2bf(f.y); u.z = f2bf(f.z); u.w = f2bf(f.w);
    return u;
}
__device__ __forceinline__ float4 fma4(float4 a, float s, float4 c) {
    c.x = fmaf(a.x, s, c.x); c.y = fmaf(a.y, s, c.y);
    c.z = fmaf(a.z, s, c.z); c.w = fmaf(a.w, s, c.w);
    return c;
}

// ---- fused: degree count (first 3E threads) + emb fp32->bf16 convert ----
__global__ void deg_cvt_kernel(const int* __restrict__ d0, const int* __restrict__ d1,
                               const int* __restrict__ d2, int* __restrict__ degi,
                               const float4* __restrict__ e0, const float4* __restrict__ e1,
                               const float4* __restrict__ e2, ushort4* __restrict__ embh,
                               int NP, int NT, int NG, int E) {
    int i = blockIdx.x * blockDim.x + threadIdx.x;
    int degN = 3 * E;
    if (i < degN) {
        int g = i / E;
        int j = i - g * E;
        const int* dd = (g == 0) ? d0 : (g == 1) ? d1 : d2;
        int base = (g == 0) ? 0 : (g == 1) ? NP : NP + NT;
        atomicAdd(&degi[base + dd[j]], 1);
        return;
    }
    int i2 = i - degN;
    int np16 = NP * 16, nt16 = NT * 16, ng16 = NG * 16;
    if (i2 >= np16 + nt16 + ng16) return;
    const float4* s; int j;
    if (i2 < np16)              { s = e0; j = i2; }
    else if (i2 < np16 + nt16)  { s = e1; j = i2 - np16; }
    else                        { s = e2; j = i2 - np16 - nt16; }
    embh[i2] = f2u4(s[j]);
}

// ---- parallel scan, stage 1: per-block (256-elem) sums ----
__global__ void block_sums(const int* __restrict__ degi, int* __restrict__ bsum, int n) {
    int i = blockIdx.x * 256 + threadIdx.x;
    int v = (i < n) ? degi[i] : 0;
#pragma unroll
    for (int s = 1; s < 64; s <<= 1) v += __shfl_xor(v, s, 64);
    __shared__ int ws[4];
    if ((threadIdx.x & 63) == 0) ws[threadIdx.x >> 6] = v;
    __syncthreads();
    if (threadIdx.x == 0) bsum[blockIdx.x] = ws[0] + ws[1] + ws[2] + ws[3];
}

// ---- stage 2: exclusive scan of block sums (single block, nb <= 1024) ----
__global__ void scan_bsums(int* __restrict__ bsum, int nb) {
    int lane = threadIdx.x & 63, wid = threadIdx.x >> 6;
    int v = (threadIdx.x < nb) ? bsum[threadIdx.x] : 0;
    int x = v;
#pragma unroll
    for (int s = 1; s < 64; s <<= 1) {
        int y = __shfl_up(x, s, 64);
        if (lane >= s) x += y;
    }
    __shared__ int ws[16];
    if (lane == 63) ws[wid] = x;
    __syncthreads();
    int pre = 0;
    for (int w2 = 0; w2 < wid; ++w2) pre += ws[w2];
    if (threadIdx.x < nb) bsum[threadIdx.x] = pre + x - v;   // exclusive
}

// ---- stage 3: global exclusive offsets + cursor copy + dinv ----
__global__ void scatter_offs(const int* __restrict__ degi, const int* __restrict__ bpre,
                             int* __restrict__ offs, int* __restrict__ cur,
                             float* __restrict__ dinv, int n, int total) {
    int i = blockIdx.x * 256 + threadIdx.x;
    int lane = threadIdx.x & 63, wid = threadIdx.x >> 6;
    int v = (i < n) ? degi[i] : 0;
    int x = v;
#pragma unroll
    for (int s = 1; s < 64; s <<= 1) {
        int y = __shfl_up(x, s, 64);
        if (lane >= s) x += y;
    }
    __shared__ int ws[4];
    if (lane == 63) ws[wid] = x;
    __syncthreads();
    int pre = bpre[blockIdx.x];
    for (int w2 = 0; w2 < wid; ++w2) pre += ws[w2];
    if (i < n) {
        int e = pre + x - v;
        offs[i] = e; cur[i] = e;
        dinv[i] = (v > 0) ? rsqrtf((float)v) : 0.0f;
    }
    if (i == 0) offs[n] = total;
}

// ---- permute all 3E edges into dst-sorted CSR order (4 B src-index payload) ----
// XCD-range-partitioned: block b handles dst-range r = b&7 of graph/chunk c = b>>3.
__global__ void permute3_kernel(const int* __restrict__ up, const int* __restrict__ ut,
                                const int* __restrict__ ug, int* __restrict__ cur,
                                int* __restrict__ ei, int NP, int NT, int NG, int E,
                                int CP) {
    int r = blockIdx.x & 7;          // dst range (intended XCD)
    int c = blockIdx.x >> 3;         // chunk index across the 3 graphs
    int g = (c >= 2 * CP) ? 2 : (c >= CP) ? 1 : 0;
    int lc = c - g * CP;
    const int* edge = (g == 0) ? up : (g == 1) ? ut : ug;
    int nb = (g == 0) ? 0 : (g == 1) ? NP : NP + NT;
    int Ng = (g == 0) ? NP : (g == 1) ? NT : NG;
    int Q  = (Ng + 7) >> 3;
    int lo = r * Q;
    int hi = lo + Q; if (hi > Ng) hi = Ng;
    int base = lc * 2048 + threadIdx.x;
#pragma unroll
    for (int u = 0; u < 8; ++u) {
        int j = base + u * 256;
        if (j < E) {
            int t = edge[E + j];                     // dst (local id)
            if (t >= lo && t < hi) {
                int s = edge[j] + nb;                // src (global id)
                int p = atomicAdd(&cur[t + nb], 1);
                ei[p] = s;
            }
        }
    }
}

// ---- conv layer 1: x1[n] = dinv[n] * sum_in emb[s]*dinv[s]  (bf16 rows) ----
__global__ void conv_csr1(const int* __restrict__ offs, const int* __restrict__ ei,
                          const float* __restrict__ dinv,
                          const ushort4* __restrict__ xin, ushort4* __restrict__ xout, int N) {
    int gid = blockIdx.x * blockDim.x + threadIdx.x;
    int n = gid >> 4, l = gid & 15;
    if (n >= N) return;
    int beg = offs[n], end = offs[n + 1];
    float4 acc = {0.f, 0.f, 0.f, 0.f};
    int k = beg;
    for (; k + 3 < end; k += 4) {
        int s0 = ei[k], s1 = ei[k + 1], s2 = ei[k + 2], s3 = ei[k + 3];
        float w0 = dinv[s0], w1 = dinv[s1], w2 = dinv[s2], w3 = dinv[s3];
        ushort4 u0 = xin[(size_t)s0 * 16 + l];
        ushort4 u1 = xin[(size_t)s1 * 16 + l];
        ushort4 u2 = xin[(size_t)s2 * 16 + l];
        ushort4 u3 = xin[(size_t)s3 * 16 + l];
        acc = fma4(u2f4(u0), w0, acc);
        acc = fma4(u2f4(u1), w1, acc);
        acc = fma4(u2f4(u2), w2, acc);
        acc = fma4(u2f4(u3), w3, acc);
    }
    for (; k < end; ++k) {
        int s = ei[k];
        acc = fma4(u2f4(xin[(size_t)s * 16 + l]), dinv[s], acc);
    }
    float sc = dinv[n];
    float4 r; r.x = acc.x * sc; r.y = acc.y * sc; r.z = acc.z * sc; r.w = acc.w * sc;
    xout[(size_t)n * 16 + l] = f2u4(r);
}

// ---- conv layer 2 + epilogue: out[n] = (emb + x1 + dinv[n]*sum x1[s]*dinv[s]) / 3 ----
__global__ void conv_csr2(const int* __restrict__ offs, const int* __restrict__ ei,
                          const float* __restrict__ dinv,
                          const ushort4* __restrict__ emb, const ushort4* __restrict__ x1,
                          ushort4* __restrict__ out, int N) {
    int gid = blockIdx.x * blockDim.x + threadIdx.x;
    int n = gid >> 4, l = gid & 15;
    if (n >= N) return;
    int beg = offs[n], end = offs[n + 1];
    float4 acc = {0.f, 0.f, 0.f, 0.f};
    int k = beg;
    for (; k + 3 < end; k += 4) {
        int s0 = ei[k], s1 = ei[k + 1], s2 = ei[k + 2], s3 = ei[k + 3];
        float w0 = dinv[s0], w1 = dinv[s1], w2 = dinv[s2], w3 = dinv[s3];
        ushort4 u0 = x1[(size_t)s0 * 16 + l];
        ushort4 u1 = x1[(size_t)s1 * 16 + l];
        ushort4 u2 = x1[(size_t)s2 * 16 + l];
        ushort4 u3 = x1[(size_t)s3 * 16 + l];
        acc = fma4(u2f4(u0), w0, acc);
        acc = fma4(u2f4(u1), w1, acc);
        acc = fma4(u2f4(u2), w2, acc);
        acc = fma4(u2f4(u3), w3, acc);
    }
    for (; k < end; ++k) {
        int s = ei[k];
        acc = fma4(u2f4(x1[(size_t)s * 16 + l]), dinv[s], acc);
    }
    float sc = dinv[n];
    size_t idx = (size_t)n * 16 + l;
    float4 em = u2f4(emb[idx]), x = u2f4(x1[idx]);
    const float third = 1.0f / 3.0f;
    float4 o;
    o.x = (em.x + x.x + acc.x * sc) * third;
    o.y = (em.y + x.y + acc.y * sc) * third;
    o.z = (em.z + x.z + acc.z * sc) * third;
    o.w = (em.w + x.w + acc.w * sc) * third;
    out[idx] = f2u4(o);
}

// ---- final v3b: wave-per-edge, no LDS arrays ----
// One wave handles EPW edges; per edge, lane l owns output dim l.
// Edge index is wave-uniform -> edge indices + 16-float feature rows load via
// the scalar pipe (uniform addresses), immune to the gathers' vmcnt queue.
// Weights live in VGPRs (lane l holds column l of W, reused over EPW edges).
// O-row gathers: one coalesced 128B row per instruction, issued 4 edges ahead
// and pinned above the GEMM with sched_barrier(0) (round-1 lesson: without the
// pin the compiler sinks gathers to their use site).
// Reduction: plain __shfl_xor chain (proven in this harness; round-2's DPP
// row_bcast variant is the prime suspect for the container crash).
__global__ __launch_bounds__(256, 4) void final_kernel(
        const int* __restrict__ up_e, const int* __restrict__ ut_e,
        const int* __restrict__ utag_e,
        const float* __restrict__ src_feat, const float* __restrict__ dst_feat,
        const unsigned short* __restrict__ O,
        const float* __restrict__ W_s, const float* __restrict__ b_s,
        const float* __restrict__ W_d, const float* __restrict__ b_d,
        float* __restrict__ out, int E, int NP, int NT) {
    int lane = threadIdx.x & 63;
    int wid  = threadIdx.x >> 6;
    int ebase = (blockIdx.x * 4 + wid) * EPW;
    if (ebase >= E) return;

    // weight columns (32 VGPRs), biases — loaded once per wave
    float Wsr[16], Wdr[16];
#pragma unroll
    for (int k = 0; k < 16; ++k) {
        Wsr[k] = W_s[k * 64 + lane];
        Wdr[k] = W_d[k * 64 + lane];
    }
    float bsr = b_s[lane], bdr = b_d[lane];
    const float third = 1.0f / 3.0f;

    for (int i0 = 0; i0 < EPW; i0 += 4) {
        int e0 = ebase + i0;
        if (e0 >= E) break;

        // scalar index loads (uniform addresses)
        int ec[4], rs[4][3], rd[4][3];
#pragma unroll
        for (int j = 0; j < 4; ++j) {
            int e = e0 + j;
            ec[j] = (e < E) ? e : (E - 1);
            rs[j][0] = up_e[ec[j]];
            rd[j][0] = up_e[E + ec[j]];
            rs[j][1] = ut_e[ec[j]] + NP;
            rd[j][1] = ut_e[E + ec[j]] + NP;
            rs[j][2] = utag_e[ec[j]] + NP + NT;
            rd[j][2] = utag_e[E + ec[j]] + NP + NT;
        }

        // issue 24 row gathers (each = one coalesced 128B row)
        unsigned short ga[4][3], gb[4][3];
#pragma unroll
        for (int j = 0; j < 4; ++j) {
#pragma unroll
            for (int t = 0; t < 3; ++t) {
                ga[j][t] = O[(size_t)rs[j][t] * 64 + lane];
                gb[j][t] = O[(size_t)rd[j][t] * 64 + lane];
            }
        }
        __builtin_amdgcn_sched_barrier(0);   // keep gathers issued above the GEMM

        // feature linears: uniform feature loads x VGPR weight columns
        float fsv[4], fdv[4];
#pragma unroll
        for (int j = 0; j < 4; ++j) {
            const float* fr = src_feat + (size_t)ec[j] * 16;
            const float* gr = dst_feat + (size_t)ec[j] * 16;
            float a = bsr, b = bdr;
#pragma unroll
            for (int k = 0; k < 16; ++k) {
                a = fmaf(fr[k], Wsr[k], a);
                b = fmaf(gr[k], Wdr[k], b);
            }
            fsv[j] = a; fdv[j] = b;
        }

        // epilogue: P·Q, wave-64 shfl_xor reduction, lane 0 stores
#pragma unroll
        for (int j = 0; j < 4; ++j) {
            float P = (bf2f(ga[j][0]) + bf2f(ga[j][1]) + bf2f(ga[j][2])) * third + fsv[j];
            float Q = (bf2f(gb[j][0]) + bf2f(gb[j][1]) + bf2f(gb[j][2])) * third + fdv[j];
            float p = P * Q;
            p += __shfl_xor(p, 32, 64);
            p += __shfl_xor(p, 16, 64);
            p += __shfl_xor(p, 8, 64);
            p += __shfl_xor(p, 4, 64);
            p += __shfl_xor(p, 2, 64);
            p += __shfl_xor(p, 1, 64);
            if (lane == 0 && e0 + j < E) out[e0 + j] = p;
        }
    }
}

extern "C" void kernel_launch(void* const* d_in, const int* in_sizes, int n_in,
                              void* d_out, int out_size, void* d_ws, size_t ws_size,
                              hipStream_t stream) {
    const int*   up_e     = (const int*)d_in[0];
    const int*   ut_e     = (const int*)d_in[1];
    const int*   utag_e   = (const int*)d_in[2];
    const float* src_feat = (const float*)d_in[3];
    const float* dst_feat = (const float*)d_in[4];
    const float* up_emb   = (const float*)d_in[5];
    const float* ut_emb   = (const float*)d_in[6];
    const float* utag_emb = (const float*)d_in[7];
    const float* W_src    = (const float*)d_in[8];
    const float* b_src    = (const float*)d_in[9];
    const float* W_dst    = (const float*)d_in[10];
    const float* b_dst    = (const float*)d_in[11];
    float* out = (float*)d_out;

    const int E  = in_sizes[0] / 2;
    const int NP = in_sizes[5] / DIM;
    const int NT = in_sizes[6] / DIM;
    const int NG = in_sizes[7] / DIM;
    const int NTOT = NP + NT + NG;
    const int NB = (NTOT + 255) / 256;          // scan blocks

    // ---- workspace layout ----
    char* w = (char*)d_ws;
    int*  degi = (int*)w;                       w += (size_t)NTOT * 4;
    int*  offs = (int*)w;                       w += (size_t)(NTOT + 1) * 4;
    int*  cur  = (int*)w;                       w += (size_t)NTOT * 4;
    int*  bsum = (int*)w;                       w += (size_t)1024 * 4;
    float* dinv = (float*)w;                    w += (size_t)NTOT * 4;
    w = (char*)(((uintptr_t)w + 127) & ~(uintptr_t)127);
    int*  ei   = (int*)w;                       w += (size_t)3 * E * 4;
    w = (char*)(((uintptr_t)w + 127) & ~(uintptr_t)127);
    ushort4* embh = (ushort4*)w;                w += (size_t)NTOT * 16 * 8;   // bf16 emb
    ushort4* x1h  = (ushort4*)w;                w += (size_t)NTOT * 16 * 8;   // bf16 x1
    ushort4* outh = (ushort4*)w;                // bf16 aggregated node table

    const int BT = 256;

    hipMemsetAsync(degi, 0, (size_t)NTOT * 4, stream);

    // fused degree count + emb bf16 convert
    {
        long long tot = 3LL * E + (long long)NTOT * 16;
        deg_cvt_kernel<<<dim3((tot + BT - 1) / BT), dim3(BT), 0, stream>>>(
            up_e + E, ut_e + E, utag_e + E, degi,
            (const float4*)up_emb, (const float4*)ut_emb, (const float4*)utag_emb,
            embh, NP, NT, NG, E);
    }

    // global parallel exclusive scan over all nodes (+ dinv)
    block_sums<<<dim3(NB), dim3(BT), 0, stream>>>(degi, bsum, NTOT);
    scan_bsums<<<dim3(1), dim3(1024), 0, stream>>>(bsum, NB);
    scatter_offs<<<dim3(NB), dim3(BT), 0, stream>>>(degi, bsum, offs, cur, dinv, NTOT, 3 * E);

    // XCD-range-partitioned CSR build: (3 graphs x CP chunks) x (8 ranges)
    {
        int CP = (E + 2047) / 2048;             // chunks per graph (2048 edges each)
        permute3_kernel<<<dim3(8 * 3 * CP), dim3(BT), 0, stream>>>(
            up_e, ut_e, utag_e, cur, ei, NP, NT, NG, E, CP);
    }

    // conv layers over ALL nodes
    int nb = ((size_t)NTOT * 16 + BT - 1) / BT;
    conv_csr1<<<dim3(nb), dim3(BT), 0, stream>>>(offs, ei, dinv, embh, x1h, NTOT);
    conv_csr2<<<dim3(nb), dim3(BT), 0, stream>>>(offs, ei, dinv, embh, x1h, outh, NTOT);

    // final v3b: wave-per-edge; 4 waves/block, EPW edges per wave
    {
        int blocks = (E + 4 * EPW - 1) / (4 * EPW);
        final_kernel<<<dim3(blocks), dim3(BT), 0, stream>>>(
            up_e, ut_e, utag_e, src_feat, dst_feat, (const unsigned short*)outh,
            W_src, b_src, W_dst, b_dst, out, E, NP, NT);
    }
}

// Round 5
// 604.127 us; speedup vs baseline: 1.5455x; 1.5455x over previous
//
#include <hip/hip_runtime.h>

#define DIM 64
#define EPW 32   // edges per wave in final_kernel

__device__ __forceinline__ float bf2f(unsigned short u) {
    union { unsigned int i; float f; } v; v.i = ((unsigned int)u) << 16; return v.f;
}
__device__ __forceinline__ unsigned short f2bf(float f) {
    union { float f; unsigned int i; } v; v.f = f;
    unsigned int r = v.i + 0x7fff + ((v.i >> 16) & 1);   // RNE (no NaN inputs here)
    return (unsigned short)(r >> 16);
}
__device__ __forceinline__ float4 u2f4(ushort4 u) {
    float4 f; f.x = bf2f(u.x); f.y = bf2f(u.y); f.z = bf2f(u.z); f.w = bf2f(u.w);
    return f;
}
__device__ __forceinline__ ushort4 f2u4(float4 f) {
    ushort4 u; u.x = f2bf(f.x); u.y = f2bf(f.y); u.z = f2bf(f.z); u.w = f2bf(f.w);
    return u;
}
__device__ __forceinline__ float4 fma4(float4 a, float s, float4 c) {
    c.x = fmaf(a.x, s, c.x); c.y = fmaf(a.y, s, c.y);
    c.z = fmaf(a.z, s, c.z); c.w = fmaf(a.w, s, c.w);
    return c;
}

// ---- fused: degree count (first 3E threads) + emb fp32->bf16 convert ----
__global__ void deg_cvt_kernel(const int* __restrict__ d0, const int* __restrict__ d1,
                               const int* __restrict__ d2, int* __restrict__ degi,
                               const float4* __restrict__ e0, const float4* __restrict__ e1,
                               const float4* __restrict__ e2, ushort4* __restrict__ embh,
                               int NP, int NT, int NG, int E) {
    int i = blockIdx.x * blockDim.x + threadIdx.x;
    int degN = 3 * E;
    if (i < degN) {
        int g = i / E;
        int j = i - g * E;
        const int* dd = (g == 0) ? d0 : (g == 1) ? d1 : d2;
        int base = (g == 0) ? 0 : (g == 1) ? NP : NP + NT;
        atomicAdd(&degi[base + dd[j]], 1);
        return;
    }
    int i2 = i - degN;
    int np16 = NP * 16, nt16 = NT * 16, ng16 = NG * 16;
    if (i2 >= np16 + nt16 + ng16) return;
    const float4* s; int j;
    if (i2 < np16)              { s = e0; j = i2; }
    else if (i2 < np16 + nt16)  { s = e1; j = i2 - np16; }
    else                        { s = e2; j = i2 - np16 - nt16; }
    embh[i2] = f2u4(s[j]);
}

// ---- parallel scan, stage 1: per-block (256-elem) sums ----
__global__ void block_sums(const int* __restrict__ degi, int* __restrict__ bsum, int n) {
    int i = blockIdx.x * 256 + threadIdx.x;
    int v = (i < n) ? degi[i] : 0;
#pragma unroll
    for (int s = 1; s < 64; s <<= 1) v += __shfl_xor(v, s, 64);
    __shared__ int ws[4];
    if ((threadIdx.x & 63) == 0) ws[threadIdx.x >> 6] = v;
    __syncthreads();
    if (threadIdx.x == 0) bsum[blockIdx.x] = ws[0] + ws[1] + ws[2] + ws[3];
}

// ---- stage 2: exclusive scan of block sums (single block, nb <= 1024) ----
__global__ void scan_bsums(int* __restrict__ bsum, int nb) {
    int lane = threadIdx.x & 63, wid = threadIdx.x >> 6;
    int v = (threadIdx.x < nb) ? bsum[threadIdx.x] : 0;
    int x = v;
#pragma unroll
    for (int s = 1; s < 64; s <<= 1) {
        int y = __shfl_up(x, s, 64);
        if (lane >= s) x += y;
    }
    __shared__ int ws[16];
    if (lane == 63) ws[wid] = x;
    __syncthreads();
    int pre = 0;
    for (int w2 = 0; w2 < wid; ++w2) pre += ws[w2];
    if (threadIdx.x < nb) bsum[threadIdx.x] = pre + x - v;   // exclusive
}

// ---- stage 3: global exclusive offsets + cursor copy + dinv ----
__global__ void scatter_offs(const int* __restrict__ degi, const int* __restrict__ bpre,
                             int* __restrict__ offs, int* __restrict__ cur,
                             float* __restrict__ dinv, int n, int total) {
    int i = blockIdx.x * 256 + threadIdx.x;
    int lane = threadIdx.x & 63, wid = threadIdx.x >> 6;
    int v = (i < n) ? degi[i] : 0;
    int x = v;
#pragma unroll
    for (int s = 1; s < 64; s <<= 1) {
        int y = __shfl_up(x, s, 64);
        if (lane >= s) x += y;
    }
    __shared__ int ws[4];
    if (lane == 63) ws[wid] = x;
    __syncthreads();
    int pre = bpre[blockIdx.x];
    for (int w2 = 0; w2 < wid; ++w2) pre += ws[w2];
    if (i < n) {
        int e = pre + x - v;
        offs[i] = e; cur[i] = e;
        dinv[i] = (v > 0) ? rsqrtf((float)v) : 0.0f;
    }
    if (i == 0) offs[n] = total;
}

// ---- permute all 3E edges into dst-sorted CSR order (4 B src-index payload) ----
// XCD-range-partitioned: block b handles dst-range r = b&7 of graph/chunk c = b>>3.
__global__ void permute3_kernel(const int* __restrict__ up, const int* __restrict__ ut,
                                const int* __restrict__ ug, int* __restrict__ cur,
                                int* __restrict__ ei, int NP, int NT, int NG, int E,
                                int CP) {
    int r = blockIdx.x & 7;          // dst range (intended XCD)
    int c = blockIdx.x >> 3;         // chunk index across the 3 graphs
    int g = (c >= 2 * CP) ? 2 : (c >= CP) ? 1 : 0;
    int lc = c - g * CP;
    const int* edge = (g == 0) ? up : (g == 1) ? ut : ug;
    int nb = (g == 0) ? 0 : (g == 1) ? NP : NP + NT;
    int Ng = (g == 0) ? NP : (g == 1) ? NT : NG;
    int Q  = (Ng + 7) >> 3;
    int lo = r * Q;
    int hi = lo + Q; if (hi > Ng) hi = Ng;
    int base = lc * 2048 + threadIdx.x;
#pragma unroll
    for (int u = 0; u < 8; ++u) {
        int j = base + u * 256;
        if (j < E) {
            int t = edge[E + j];                     // dst (local id)
            if (t >= lo && t < hi) {
                int s = edge[j] + nb;                // src (global id)
                int p = atomicAdd(&cur[t + nb], 1);
                ei[p] = s;
            }
        }
    }
}

// ---- conv layer 1: x1[n] = dinv[n] * sum_in emb[s]*dinv[s]  (bf16 rows) ----
__global__ void conv_csr1(const int* __restrict__ offs, const int* __restrict__ ei,
                          const float* __restrict__ dinv,
                          const ushort4* __restrict__ xin, ushort4* __restrict__ xout, int N) {
    int gid = blockIdx.x * blockDim.x + threadIdx.x;
    int n = gid >> 4, l = gid & 15;
    if (n >= N) return;
    int beg = offs[n], end = offs[n + 1];
    float4 acc = {0.f, 0.f, 0.f, 0.f};
    int k = beg;
    for (; k + 3 < end; k += 4) {
        int s0 = ei[k], s1 = ei[k + 1], s2 = ei[k + 2], s3 = ei[k + 3];
        float w0 = dinv[s0], w1 = dinv[s1], w2 = dinv[s2], w3 = dinv[s3];
        ushort4 u0 = xin[(size_t)s0 * 16 + l];
        ushort4 u1 = xin[(size_t)s1 * 16 + l];
        ushort4 u2 = xin[(size_t)s2 * 16 + l];
        ushort4 u3 = xin[(size_t)s3 * 16 + l];
        acc = fma4(u2f4(u0), w0, acc);
        acc = fma4(u2f4(u1), w1, acc);
        acc = fma4(u2f4(u2), w2, acc);
        acc = fma4(u2f4(u3), w3, acc);
    }
    for (; k < end; ++k) {
        int s = ei[k];
        acc = fma4(u2f4(xin[(size_t)s * 16 + l]), dinv[s], acc);
    }
    float sc = dinv[n];
    float4 r; r.x = acc.x * sc; r.y = acc.y * sc; r.z = acc.z * sc; r.w = acc.w * sc;
    xout[(size_t)n * 16 + l] = f2u4(r);
}

// ---- conv layer 2 + epilogue: out[n] = (emb + x1 + dinv[n]*sum x1[s]*dinv[s]) / 3 ----
__global__ void conv_csr2(const int* __restrict__ offs, const int* __restrict__ ei,
                          const float* __restrict__ dinv,
                          const ushort4* __restrict__ emb, const ushort4* __restrict__ x1,
                          ushort4* __restrict__ out, int N) {
    int gid = blockIdx.x * blockDim.x + threadIdx.x;
    int n = gid >> 4, l = gid & 15;
    if (n >= N) return;
    int beg = offs[n], end = offs[n + 1];
    float4 acc = {0.f, 0.f, 0.f, 0.f};
    int k = beg;
    for (; k + 3 < end; k += 4) {
        int s0 = ei[k], s1 = ei[k + 1], s2 = ei[k + 2], s3 = ei[k + 3];
        float w0 = dinv[s0], w1 = dinv[s1], w2 = dinv[s2], w3 = dinv[s3];
        ushort4 u0 = x1[(size_t)s0 * 16 + l];
        ushort4 u1 = x1[(size_t)s1 * 16 + l];
        ushort4 u2 = x1[(size_t)s2 * 16 + l];
        ushort4 u3 = x1[(size_t)s3 * 16 + l];
        acc = fma4(u2f4(u0), w0, acc);
        acc = fma4(u2f4(u1), w1, acc);
        acc = fma4(u2f4(u2), w2, acc);
        acc = fma4(u2f4(u3), w3, acc);
    }
    for (; k < end; ++k) {
        int s = ei[k];
        acc = fma4(u2f4(x1[(size_t)s * 16 + l]), dinv[s], acc);
    }
    float sc = dinv[n];
    size_t idx = (size_t)n * 16 + l;
    float4 em = u2f4(emb[idx]), x = u2f4(x1[idx]);
    const float third = 1.0f / 3.0f;
    float4 o;
    o.x = (em.x + x.x + acc.x * sc) * third;
    o.y = (em.y + x.y + acc.y * sc) * third;
    o.z = (em.z + x.z + acc.z * sc) * third;
    o.w = (em.w + x.w + acc.w * sc) * third;
    out[idx] = f2u4(o);
}

// ---- final v4: wave-per-edge, no LDS, NO OCCUPANCY FLOOR ----
// Round-3 post-mortem: __launch_bounds__(256,4) forced a 64-VGPR target; the
// ~110 live registers (32 weight cols + 24 in-flight gathers + indices) spilled
// to scratch -> 854 MB of scratch writes, 586 us. Fix: let the allocator keep
// everything in VGPRs (~128, 4 waves/SIMD). Index liveness shortened: rs/rd
// are consumed immediately at gather issue; only ec[4] survives to the GEMM.
__global__ __launch_bounds__(256) void final_kernel(
        const int* __restrict__ up_e, const int* __restrict__ ut_e,
        const int* __restrict__ utag_e,
        const float* __restrict__ src_feat, const float* __restrict__ dst_feat,
        const unsigned short* __restrict__ O,
        const float* __restrict__ W_s, const float* __restrict__ b_s,
        const float* __restrict__ W_d, const float* __restrict__ b_d,
        float* __restrict__ out, int E, int NP, int NT) {
    int lane = threadIdx.x & 63;
    int wid  = threadIdx.x >> 6;
    int ebase = (blockIdx.x * 4 + wid) * EPW;
    if (ebase >= E) return;

    // weight columns (32 VGPRs), biases — loaded once per wave
    float Wsr[16], Wdr[16];
#pragma unroll
    for (int k = 0; k < 16; ++k) {
        Wsr[k] = W_s[k * 64 + lane];
        Wdr[k] = W_d[k * 64 + lane];
    }
    float bsr = b_s[lane], bdr = b_d[lane];
    const float third = 1.0f / 3.0f;

    for (int i0 = 0; i0 < EPW; i0 += 4) {
        int e0 = ebase + i0;
        if (e0 >= E) break;

        // per-edge clamped indices (kept live for the feature phase)
        int ec[4];
#pragma unroll
        for (int j = 0; j < 4; ++j) {
            int e = e0 + j;
            ec[j] = (e < E) ? e : (E - 1);
        }

        // issue 24 row gathers; edge-index loads consumed immediately
        unsigned short ga[4][3], gb[4][3];
#pragma unroll
        for (int j = 0; j < 4; ++j) {
            int r0 = up_e[ec[j]];
            int r1 = up_e[E + ec[j]];
            ga[j][0] = O[(size_t)r0 * 64 + lane];
            gb[j][0] = O[(size_t)r1 * 64 + lane];
            int r2 = ut_e[ec[j]] + NP;
            int r3 = ut_e[E + ec[j]] + NP;
            ga[j][1] = O[(size_t)r2 * 64 + lane];
            gb[j][1] = O[(size_t)r3 * 64 + lane];
            int r4 = utag_e[ec[j]] + NP + NT;
            int r5 = utag_e[E + ec[j]] + NP + NT;
            ga[j][2] = O[(size_t)r4 * 64 + lane];
            gb[j][2] = O[(size_t)r5 * 64 + lane];
        }
        __builtin_amdgcn_sched_barrier(0);   // keep gathers issued above the GEMM

        // feature linears: uniform feature loads x VGPR weight columns
        float fsv[4], fdv[4];
#pragma unroll
        for (int j = 0; j < 4; ++j) {
            const float* fr = src_feat + (size_t)ec[j] * 16;
            const float* gr = dst_feat + (size_t)ec[j] * 16;
            float a = bsr, b = bdr;
#pragma unroll
            for (int k = 0; k < 16; ++k) {
                a = fmaf(fr[k], Wsr[k], a);
                b = fmaf(gr[k], Wdr[k], b);
            }
            fsv[j] = a; fdv[j] = b;
        }

        // epilogue: P·Q, wave-64 shfl_xor reduction, lane 0 stores
#pragma unroll
        for (int j = 0; j < 4; ++j) {
            float P = (bf2f(ga[j][0]) + bf2f(ga[j][1]) + bf2f(ga[j][2])) * third + fsv[j];
            float Q = (bf2f(gb[j][0]) + bf2f(gb[j][1]) + bf2f(gb[j][2])) * third + fdv[j];
            float p = P * Q;
            p += __shfl_xor(p, 32, 64);
            p += __shfl_xor(p, 16, 64);
            p += __shfl_xor(p, 8, 64);
            p += __shfl_xor(p, 4, 64);
            p += __shfl_xor(p, 2, 64);
            p += __shfl_xor(p, 1, 64);
            if (lane == 0 && e0 + j < E) out[e0 + j] = p;
        }
    }
}

extern "C" void kernel_launch(void* const* d_in, const int* in_sizes, int n_in,
                              void* d_out, int out_size, void* d_ws, size_t ws_size,
                              hipStream_t stream) {
    const int*   up_e     = (const int*)d_in[0];
    const int*   ut_e     = (const int*)d_in[1];
    const int*   utag_e   = (const int*)d_in[2];
    const float* src_feat = (const float*)d_in[3];
    const float* dst_feat = (const float*)d_in[4];
    const float* up_emb   = (const float*)d_in[5];
    const float* ut_emb   = (const float*)d_in[6];
    const float* utag_emb = (const float*)d_in[7];
    const float* W_src    = (const float*)d_in[8];
    const float* b_src    = (const float*)d_in[9];
    const float* W_dst    = (const float*)d_in[10];
    const float* b_dst    = (const float*)d_in[11];
    float* out = (float*)d_out;

    const int E  = in_sizes[0] / 2;
    const int NP = in_sizes[5] / DIM;
    const int NT = in_sizes[6] / DIM;
    const int NG = in_sizes[7] / DIM;
    const int NTOT = NP + NT + NG;
    const int NB = (NTOT + 255) / 256;          // scan blocks

    // ---- workspace layout ----
    char* w = (char*)d_ws;
    int*  degi = (int*)w;                       w += (size_t)NTOT * 4;
    int*  offs = (int*)w;                       w += (size_t)(NTOT + 1) * 4;
    int*  cur  = (int*)w;                       w += (size_t)NTOT * 4;
    int*  bsum = (int*)w;                       w += (size_t)1024 * 4;
    float* dinv = (float*)w;                    w += (size_t)NTOT * 4;
    w = (char*)(((uintptr_t)w + 127) & ~(uintptr_t)127);
    int*  ei   = (int*)w;                       w += (size_t)3 * E * 4;
    w = (char*)(((uintptr_t)w + 127) & ~(uintptr_t)127);
    ushort4* embh = (ushort4*)w;                w += (size_t)NTOT * 16 * 8;   // bf16 emb
    ushort4* x1h  = (ushort4*)w;                w += (size_t)NTOT * 16 * 8;   // bf16 x1
    ushort4* outh = (ushort4*)w;                // bf16 aggregated node table

    const int BT = 256;

    hipMemsetAsync(degi, 0, (size_t)NTOT * 4, stream);

    // fused degree count + emb bf16 convert
    {
        long long tot = 3LL * E + (long long)NTOT * 16;
        deg_cvt_kernel<<<dim3((tot + BT - 1) / BT), dim3(BT), 0, stream>>>(
            up_e + E, ut_e + E, utag_e + E, degi,
            (const float4*)up_emb, (const float4*)ut_emb, (const float4*)utag_emb,
            embh, NP, NT, NG, E);
    }

    // global parallel exclusive scan over all nodes (+ dinv)
    block_sums<<<dim3(NB), dim3(BT), 0, stream>>>(degi, bsum, NTOT);
    scan_bsums<<<dim3(1), dim3(1024), 0, stream>>>(bsum, NB);
    scatter_offs<<<dim3(NB), dim3(BT), 0, stream>>>(degi, bsum, offs, cur, dinv, NTOT, 3 * E);

    // XCD-range-partitioned CSR build: (3 graphs x CP chunks) x (8 ranges)
    {
        int CP = (E + 2047) / 2048;             // chunks per graph (2048 edges each)
        permute3_kernel<<<dim3(8 * 3 * CP), dim3(BT), 0, stream>>>(
            up_e, ut_e, utag_e, cur, ei, NP, NT, NG, E, CP);
    }

    // conv layers over ALL nodes
    int nb = ((size_t)NTOT * 16 + BT - 1) / BT;
    conv_csr1<<<dim3(nb), dim3(BT), 0, stream>>>(offs, ei, dinv, embh, x1h, NTOT);
    conv_csr2<<<dim3(nb), dim3(BT), 0, stream>>>(offs, ei, dinv, embh, x1h, outh, NTOT);

    // final v4: wave-per-edge; 4 waves/block, EPW edges per wave
    {
        int blocks = (E + 4 * EPW - 1) / (4 * EPW);
        final_kernel<<<dim3(blocks), dim3(BT), 0, stream>>>(
            up_e, ut_e, utag_e, src_feat, dst_feat, (const unsigned short*)outh,
            W_src, b_src, W_dst, b_dst, out, E, NP, NT);
    }
}

// Round 6
// 471.922 us; speedup vs baseline: 1.9785x; 1.2801x over previous
//
#include <hip/hip_runtime.h>

#define DIM 64

__device__ __forceinline__ float bf2f(unsigned short u) {
    union { unsigned int i; float f; } v; v.i = ((unsigned int)u) << 16; return v.f;
}
__device__ __forceinline__ unsigned short f2bf(float f) {
    union { float f; unsigned int i; } v; v.f = f;
    unsigned int r = v.i + 0x7fff + ((v.i >> 16) & 1);   // RNE (no NaN inputs here)
    return (unsigned short)(r >> 16);
}
__device__ __forceinline__ float4 u2f4(ushort4 u) {
    float4 f; f.x = bf2f(u.x); f.y = bf2f(u.y); f.z = bf2f(u.z); f.w = bf2f(u.w);
    return f;
}
__device__ __forceinline__ ushort4 f2u4(float4 f) {
    ushort4 u; u.x = f2bf(f.x); u.y = f2bf(f.y); u.z = f2bf(f.z); u.w = f2bf(f.w);
    return u;
}
__device__ __forceinline__ float4 fma4(float4 a, float s, float4 c) {
    c.x = fmaf(a.x, s, c.x); c.y = fmaf(a.y, s, c.y);
    c.z = fmaf(a.z, s, c.z); c.w = fmaf(a.w, s, c.w);
    return c;
}

// ---- fused: degree count (first 3E threads) + emb fp32->bf16 convert ----
__global__ void deg_cvt_kernel(const int* __restrict__ d0, const int* __restrict__ d1,
                               const int* __restrict__ d2, int* __restrict__ degi,
                               const float4* __restrict__ e0, const float4* __restrict__ e1,
                               const float4* __restrict__ e2, ushort4* __restrict__ embh,
                               int NP, int NT, int NG, int E) {
    int i = blockIdx.x * blockDim.x + threadIdx.x;
    int degN = 3 * E;
    if (i < degN) {
        int g = i / E;
        int j = i - g * E;
        const int* dd = (g == 0) ? d0 : (g == 1) ? d1 : d2;
        int base = (g == 0) ? 0 : (g == 1) ? NP : NP + NT;
        atomicAdd(&degi[base + dd[j]], 1);
        return;
    }
    int i2 = i - degN;
    int np16 = NP * 16, nt16 = NT * 16, ng16 = NG * 16;
    if (i2 >= np16 + nt16 + ng16) return;
    const float4* s; int j;
    if (i2 < np16)              { s = e0; j = i2; }
    else if (i2 < np16 + nt16)  { s = e1; j = i2 - np16; }
    else                        { s = e2; j = i2 - np16 - nt16; }
    embh[i2] = f2u4(s[j]);
}

// ---- parallel scan, stage 1: per-block (256-elem) sums ----
__global__ void block_sums(const int* __restrict__ degi, int* __restrict__ bsum, int n) {
    int i = blockIdx.x * 256 + threadIdx.x;
    int v = (i < n) ? degi[i] : 0;
#pragma unroll
    for (int s = 1; s < 64; s <<= 1) v += __shfl_xor(v, s, 64);
    __shared__ int ws[4];
    if ((threadIdx.x & 63) == 0) ws[threadIdx.x >> 6] = v;
    __syncthreads();
    if (threadIdx.x == 0) bsum[blockIdx.x] = ws[0] + ws[1] + ws[2] + ws[3];
}

// ---- stage 2: exclusive scan of block sums (single block, nb <= 1024) ----
__global__ void scan_bsums(int* __restrict__ bsum, int nb) {
    int lane = threadIdx.x & 63, wid = threadIdx.x >> 6;
    int v = (threadIdx.x < nb) ? bsum[threadIdx.x] : 0;
    int x = v;
#pragma unroll
    for (int s = 1; s < 64; s <<= 1) {
        int y = __shfl_up(x, s, 64);
        if (lane >= s) x += y;
    }
    __shared__ int ws[16];
    if (lane == 63) ws[wid] = x;
    __syncthreads();
    int pre = 0;
    for (int w2 = 0; w2 < wid; ++w2) pre += ws[w2];
    if (threadIdx.x < nb) bsum[threadIdx.x] = pre + x - v;   // exclusive
}

// ---- stage 3: global exclusive offsets + cursor copy + dinv ----
__global__ void scatter_offs(const int* __restrict__ degi, const int* __restrict__ bpre,
                             int* __restrict__ offs, int* __restrict__ cur,
                             float* __restrict__ dinv, int n, int total) {
    int i = blockIdx.x * 256 + threadIdx.x;
    int lane = threadIdx.x & 63, wid = threadIdx.x >> 6;
    int v = (i < n) ? degi[i] : 0;
    int x = v;
#pragma unroll
    for (int s = 1; s < 64; s <<= 1) {
        int y = __shfl_up(x, s, 64);
        if (lane >= s) x += y;
    }
    __shared__ int ws[4];
    if (lane == 63) ws[wid] = x;
    __syncthreads();
    int pre = bpre[blockIdx.x];
    for (int w2 = 0; w2 < wid; ++w2) pre += ws[w2];
    if (i < n) {
        int e = pre + x - v;
        offs[i] = e; cur[i] = e;
        dinv[i] = (v > 0) ? rsqrtf((float)v) : 0.0f;
    }
    if (i == 0) offs[n] = total;
}

// ---- permute all 3E edges into dst-sorted CSR order (4 B src-index payload) ----
// XCD-range-partitioned: block b handles dst-range r = b&7 of graph/chunk c = b>>3.
__global__ void permute3_kernel(const int* __restrict__ up, const int* __restrict__ ut,
                                const int* __restrict__ ug, int* __restrict__ cur,
                                int* __restrict__ ei, int NP, int NT, int NG, int E,
                                int CP) {
    int r = blockIdx.x & 7;          // dst range (intended XCD)
    int c = blockIdx.x >> 3;         // chunk index across the 3 graphs
    int g = (c >= 2 * CP) ? 2 : (c >= CP) ? 1 : 0;
    int lc = c - g * CP;
    const int* edge = (g == 0) ? up : (g == 1) ? ut : ug;
    int nb = (g == 0) ? 0 : (g == 1) ? NP : NP + NT;
    int Ng = (g == 0) ? NP : (g == 1) ? NT : NG;
    int Q  = (Ng + 7) >> 3;
    int lo = r * Q;
    int hi = lo + Q; if (hi > Ng) hi = Ng;
    int base = lc * 2048 + threadIdx.x;
#pragma unroll
    for (int u = 0; u < 8; ++u) {
        int j = base + u * 256;
        if (j < E) {
            int t = edge[E + j];                     // dst (local id)
            if (t >= lo && t < hi) {
                int s = edge[j] + nb;                // src (global id)
                int p = atomicAdd(&cur[t + nb], 1);
                ei[p] = s;
            }
        }
    }
}

// ---- conv layer 1: x1[n] = dinv[n] * sum_in emb[s]*dinv[s]  (bf16 rows) ----
__global__ void conv_csr1(const int* __restrict__ offs, const int* __restrict__ ei,
                          const float* __restrict__ dinv,
                          const ushort4* __restrict__ xin, ushort4* __restrict__ xout, int N) {
    int gid = blockIdx.x * blockDim.x + threadIdx.x;
    int n = gid >> 4, l = gid & 15;
    if (n >= N) return;
    int beg = offs[n], end = offs[n + 1];
    float4 acc = {0.f, 0.f, 0.f, 0.f};
    int k = beg;
    for (; k + 3 < end; k += 4) {
        int s0 = ei[k], s1 = ei[k + 1], s2 = ei[k + 2], s3 = ei[k + 3];
        float w0 = dinv[s0], w1 = dinv[s1], w2 = dinv[s2], w3 = dinv[s3];
        ushort4 u0 = xin[(size_t)s0 * 16 + l];
        ushort4 u1 = xin[(size_t)s1 * 16 + l];
        ushort4 u2 = xin[(size_t)s2 * 16 + l];
        ushort4 u3 = xin[(size_t)s3 * 16 + l];
        acc = fma4(u2f4(u0), w0, acc);
        acc = fma4(u2f4(u1), w1, acc);
        acc = fma4(u2f4(u2), w2, acc);
        acc = fma4(u2f4(u3), w3, acc);
    }
    for (; k < end; ++k) {
        int s = ei[k];
        acc = fma4(u2f4(xin[(size_t)s * 16 + l]), dinv[s], acc);
    }
    float sc = dinv[n];
    float4 r; r.x = acc.x * sc; r.y = acc.y * sc; r.z = acc.z * sc; r.w = acc.w * sc;
    xout[(size_t)n * 16 + l] = f2u4(r);
}

// ---- conv layer 2 + epilogue: out[n] = (emb + x1 + dinv[n]*sum x1[s]*dinv[s]) / 3 ----
__global__ void conv_csr2(const int* __restrict__ offs, const int* __restrict__ ei,
                          const float* __restrict__ dinv,
                          const ushort4* __restrict__ emb, const ushort4* __restrict__ x1,
                          ushort4* __restrict__ out, int N) {
    int gid = blockIdx.x * blockDim.x + threadIdx.x;
    int n = gid >> 4, l = gid & 15;
    if (n >= N) return;
    int beg = offs[n], end = offs[n + 1];
    float4 acc = {0.f, 0.f, 0.f, 0.f};
    int k = beg;
    for (; k + 3 < end; k += 4) {
        int s0 = ei[k], s1 = ei[k + 1], s2 = ei[k + 2], s3 = ei[k + 3];
        float w0 = dinv[s0], w1 = dinv[s1], w2 = dinv[s2], w3 = dinv[s3];
        ushort4 u0 = x1[(size_t)s0 * 16 + l];
        ushort4 u1 = x1[(size_t)s1 * 16 + l];
        ushort4 u2 = x1[(size_t)s2 * 16 + l];
        ushort4 u3 = x1[(size_t)s3 * 16 + l];
        acc = fma4(u2f4(u0), w0, acc);
        acc = fma4(u2f4(u1), w1, acc);
        acc = fma4(u2f4(u2), w2, acc);
        acc = fma4(u2f4(u3), w3, acc);
    }
    for (; k < end; ++k) {
        int s = ei[k];
        acc = fma4(u2f4(x1[(size_t)s * 16 + l]), dinv[s], acc);
    }
    float sc = dinv[n];
    size_t idx = (size_t)n * 16 + l;
    float4 em = u2f4(emb[idx]), x = u2f4(x1[idx]);
    const float third = 1.0f / 3.0f;
    float4 o;
    o.x = (em.x + x.x + acc.x * sc) * third;
    o.y = (em.y + x.y + acc.y * sc) * third;
    o.z = (em.z + x.z + acc.z * sc) * third;
    o.w = (em.w + x.w + acc.w * sc) * third;
    out[idx] = f2u4(o);
}

// ---- final v5: 16-lane groups (round-1 geometry), JB=2, de-shfl'd GEMM ----
// Round-1 (84us) was LDS-pipe bound: ~10 LDS ops/edge (32 ds_read weights +
// 128 ds_bpermute __shfl broadcasts + reduce shuffles per 16 edges). Fix:
//  * features loaded REDUNDANTLY per group (4x float4, uniform addr within
//    the 16-lane group -> one 16B broadcast request/group) -> zero GEMM shfls
//  * 2 edges/group/iter so 16 feature float4 fit in VGPRs
//  * gathers pinned above the GEMM with sched_barrier(0) (round-1's compiler
//    sank them at VGPR=48; round-3 taught us NOT to add an occupancy floor)
// Phase order (in-order vmcnt): features -> indices+gathers -> GEMM (waits
// features only) -> epilogue (waits gathers). LDS ops/edge: ~10 -> ~5.
__global__ __launch_bounds__(256) void final_kernel(
        const int* __restrict__ up_e, const int* __restrict__ ut_e,
        const int* __restrict__ utag_e,
        const float4* __restrict__ SF4, const float4* __restrict__ DF4,
        const ushort4* __restrict__ O,
        const float4* __restrict__ W_s4, const float4* __restrict__ b_s4,
        const float4* __restrict__ W_d4, const float4* __restrict__ b_d4,
        float* __restrict__ out, int E, int NP, int NT) {
    __shared__ float4 LWs[256], LWd[256];
    int tid = threadIdx.x;
    LWs[tid] = W_s4[tid];          // 16x16 float4 = full [16,64] weight matrix
    LWd[tid] = W_d4[tid];
    __syncthreads();

    int gid = blockIdx.x * blockDim.x + tid;
    int grp = gid >> 4;
    int l = gid & 15;
    int e0 = grp * 2;
    if (e0 >= E) return;
    int ec0 = e0;
    int ec1 = (e0 + 1 < E) ? (e0 + 1) : (E - 1);

    // ---- phase 0: feature rows (redundant within group) + biases ----
    float4 f0a = SF4[(size_t)ec0 * 4 + 0], f0b = SF4[(size_t)ec0 * 4 + 1];
    float4 f0c = SF4[(size_t)ec0 * 4 + 2], f0d = SF4[(size_t)ec0 * 4 + 3];
    float4 g0a = DF4[(size_t)ec0 * 4 + 0], g0b = DF4[(size_t)ec0 * 4 + 1];
    float4 g0c = DF4[(size_t)ec0 * 4 + 2], g0d = DF4[(size_t)ec0 * 4 + 3];
    float4 f1a = SF4[(size_t)ec1 * 4 + 0], f1b = SF4[(size_t)ec1 * 4 + 1];
    float4 f1c = SF4[(size_t)ec1 * 4 + 2], f1d = SF4[(size_t)ec1 * 4 + 3];
    float4 g1a = DF4[(size_t)ec1 * 4 + 0], g1b = DF4[(size_t)ec1 * 4 + 1];
    float4 g1c = DF4[(size_t)ec1 * 4 + 2], g1d = DF4[(size_t)ec1 * 4 + 3];
    float4 bsv = b_s4[l], bdv = b_d4[l];

    // ---- phase 1: indices + 12 O-row gathers (8B/lane, coalesced) ----
    int sp0 = up_e[ec0],              dp0 = up_e[E + ec0];
    int st0 = ut_e[ec0] + NP,         dt0 = ut_e[E + ec0] + NP;
    int sg0 = utag_e[ec0] + NP + NT,  dg0 = utag_e[E + ec0] + NP + NT;
    int sp1 = up_e[ec1],              dp1 = up_e[E + ec1];
    int st1 = ut_e[ec1] + NP,         dt1 = ut_e[E + ec1] + NP;
    int sg1 = utag_e[ec1] + NP + NT,  dg1 = utag_e[E + ec1] + NP + NT;

    ushort4 a00 = O[(size_t)sp0 * 16 + l];
    ushort4 a01 = O[(size_t)st0 * 16 + l];
    ushort4 a02 = O[(size_t)sg0 * 16 + l];
    ushort4 b00 = O[(size_t)dp0 * 16 + l];
    ushort4 b01 = O[(size_t)dt0 * 16 + l];
    ushort4 b02 = O[(size_t)dg0 * 16 + l];
    ushort4 a10 = O[(size_t)sp1 * 16 + l];
    ushort4 a11 = O[(size_t)st1 * 16 + l];
    ushort4 a12 = O[(size_t)sg1 * 16 + l];
    ushort4 b10 = O[(size_t)dp1 * 16 + l];
    ushort4 b11 = O[(size_t)dt1 * 16 + l];
    ushort4 b12 = O[(size_t)dg1 * 16 + l];
    __builtin_amdgcn_sched_barrier(0);   // pin gathers above the GEMM

    // ---- phase 2: feature GEMM, LDS weights x register scalars (no shfl) ----
    float4 fs0 = bsv, fd0 = bdv, fs1 = bsv, fd1 = bdv;
#pragma unroll
    for (int kb = 0; kb < 4; ++kb) {
        float4 w0 = LWs[(kb * 4 + 0) * 16 + l];
        float4 w1 = LWs[(kb * 4 + 1) * 16 + l];
        float4 w2 = LWs[(kb * 4 + 2) * 16 + l];
        float4 w3 = LWs[(kb * 4 + 3) * 16 + l];
        float4 v0 = LWd[(kb * 4 + 0) * 16 + l];
        float4 v1 = LWd[(kb * 4 + 1) * 16 + l];
        float4 v2 = LWd[(kb * 4 + 2) * 16 + l];
        float4 v3 = LWd[(kb * 4 + 3) * 16 + l];
        float4 F0 = (kb == 0) ? f0a : (kb == 1) ? f0b : (kb == 2) ? f0c : f0d;
        float4 G0 = (kb == 0) ? g0a : (kb == 1) ? g0b : (kb == 2) ? g0c : g0d;
        float4 F1 = (kb == 0) ? f1a : (kb == 1) ? f1b : (kb == 2) ? f1c : f1d;
        float4 G1 = (kb == 0) ? g1a : (kb == 1) ? g1b : (kb == 2) ? g1c : g1d;
        fs0 = fma4(w0, F0.x, fs0); fs0 = fma4(w1, F0.y, fs0);
        fs0 = fma4(w2, F0.z, fs0); fs0 = fma4(w3, F0.w, fs0);
        fd0 = fma4(v0, G0.x, fd0); fd0 = fma4(v1, G0.y, fd0);
        fd0 = fma4(v2, G0.z, fd0); fd0 = fma4(v3, G0.w, fd0);
        fs1 = fma4(w0, F1.x, fs1); fs1 = fma4(w1, F1.y, fs1);
        fs1 = fma4(w2, F1.z, fs1); fs1 = fma4(w3, F1.w, fs1);
        fd1 = fma4(v0, G1.x, fd1); fd1 = fma4(v1, G1.y, fd1);
        fd1 = fma4(v2, G1.z, fd1); fd1 = fma4(v3, G1.w, fd1);
    }

    // ---- phase 3: epilogue (waits on gathers) ----
    const float third = 1.0f / 3.0f;
    {
        float4 vp = u2f4(a00), vt = u2f4(a01), vg = u2f4(a02);
        float4 P, Q;
        P.x = (vp.x + vt.x + vg.x) * third + fs0.x;
        P.y = (vp.y + vt.y + vg.y) * third + fs0.y;
        P.z = (vp.z + vt.z + vg.z) * third + fs0.z;
        P.w = (vp.w + vt.w + vg.w) * third + fs0.w;
        vp = u2f4(b00); vt = u2f4(b01); vg = u2f4(b02);
        Q.x = (vp.x + vt.x + vg.x) * third + fd0.x;
        Q.y = (vp.y + vt.y + vg.y) * third + fd0.y;
        Q.z = (vp.z + vt.z + vg.z) * third + fd0.z;
        Q.w = (vp.w + vt.w + vg.w) * third + fd0.w;
        float p = P.x * Q.x + P.y * Q.y + P.z * Q.z + P.w * Q.w;
        p += __shfl_xor(p, 8, 64);
        p += __shfl_xor(p, 4, 64);
        p += __shfl_xor(p, 2, 64);
        p += __shfl_xor(p, 1, 64);
        if (l == 0) out[e0] = p;
    }
    if (e0 + 1 < E) {
        float4 vp = u2f4(a10), vt = u2f4(a11), vg = u2f4(a12);
        float4 P, Q;
        P.x = (vp.x + vt.x + vg.x) * third + fs1.x;
        P.y = (vp.y + vt.y + vg.y) * third + fs1.y;
        P.z = (vp.z + vt.z + vg.z) * third + fs1.z;
        P.w = (vp.w + vt.w + vg.w) * third + fs1.w;
        vp = u2f4(b10); vt = u2f4(b11); vg = u2f4(b12);
        Q.x = (vp.x + vt.x + vg.x) * third + fd1.x;
        Q.y = (vp.y + vt.y + vg.y) * third + fd1.y;
        Q.z = (vp.z + vt.z + vg.z) * third + fd1.z;
        Q.w = (vp.w + vt.w + vg.w) * third + fd1.w;
        float p = P.x * Q.x + P.y * Q.y + P.z * Q.z + P.w * Q.w;
        p += __shfl_xor(p, 8, 64);
        p += __shfl_xor(p, 4, 64);
        p += __shfl_xor(p, 2, 64);
        p += __shfl_xor(p, 1, 64);
        if (l == 0) out[e0 + 1] = p;
    }
}

extern "C" void kernel_launch(void* const* d_in, const int* in_sizes, int n_in,
                              void* d_out, int out_size, void* d_ws, size_t ws_size,
                              hipStream_t stream) {
    const int*   up_e     = (const int*)d_in[0];
    const int*   ut_e     = (const int*)d_in[1];
    const int*   utag_e   = (const int*)d_in[2];
    const float* src_feat = (const float*)d_in[3];
    const float* dst_feat = (const float*)d_in[4];
    const float* up_emb   = (const float*)d_in[5];
    const float* ut_emb   = (const float*)d_in[6];
    const float* utag_emb = (const float*)d_in[7];
    const float* W_src    = (const float*)d_in[8];
    const float* b_src    = (const float*)d_in[9];
    const float* W_dst    = (const float*)d_in[10];
    const float* b_dst    = (const float*)d_in[11];
    float* out = (float*)d_out;

    const int E  = in_sizes[0] / 2;
    const int NP = in_sizes[5] / DIM;
    const int NT = in_sizes[6] / DIM;
    const int NG = in_sizes[7] / DIM;
    const int NTOT = NP + NT + NG;
    const int NB = (NTOT + 255) / 256;          // scan blocks

    // ---- workspace layout ----
    char* w = (char*)d_ws;
    int*  degi = (int*)w;                       w += (size_t)NTOT * 4;
    int*  offs = (int*)w;                       w += (size_t)(NTOT + 1) * 4;
    int*  cur  = (int*)w;                       w += (size_t)NTOT * 4;
    int*  bsum = (int*)w;                       w += (size_t)1024 * 4;
    float* dinv = (float*)w;                    w += (size_t)NTOT * 4;
    w = (char*)(((uintptr_t)w + 127) & ~(uintptr_t)127);
    int*  ei   = (int*)w;                       w += (size_t)3 * E * 4;
    w = (char*)(((uintptr_t)w + 127) & ~(uintptr_t)127);
    ushort4* embh = (ushort4*)w;                w += (size_t)NTOT * 16 * 8;   // bf16 emb
    ushort4* x1h  = (ushort4*)w;                w += (size_t)NTOT * 16 * 8;   // bf16 x1
    ushort4* outh = (ushort4*)w;                // bf16 aggregated node table

    const int BT = 256;

    hipMemsetAsync(degi, 0, (size_t)NTOT * 4, stream);

    // fused degree count + emb bf16 convert
    {
        long long tot = 3LL * E + (long long)NTOT * 16;
        deg_cvt_kernel<<<dim3((tot + BT - 1) / BT), dim3(BT), 0, stream>>>(
            up_e + E, ut_e + E, utag_e + E, degi,
            (const float4*)up_emb, (const float4*)ut_emb, (const float4*)utag_emb,
            embh, NP, NT, NG, E);
    }

    // global parallel exclusive scan over all nodes (+ dinv)
    block_sums<<<dim3(NB), dim3(BT), 0, stream>>>(degi, bsum, NTOT);
    scan_bsums<<<dim3(1), dim3(1024), 0, stream>>>(bsum, NB);
    scatter_offs<<<dim3(NB), dim3(BT), 0, stream>>>(degi, bsum, offs, cur, dinv, NTOT, 3 * E);

    // XCD-range-partitioned CSR build: (3 graphs x CP chunks) x (8 ranges)
    {
        int CP = (E + 2047) / 2048;             // chunks per graph (2048 edges each)
        permute3_kernel<<<dim3(8 * 3 * CP), dim3(BT), 0, stream>>>(
            up_e, ut_e, utag_e, cur, ei, NP, NT, NG, E, CP);
    }

    // conv layers over ALL nodes
    int nb = ((size_t)NTOT * 16 + BT - 1) / BT;
    conv_csr1<<<dim3(nb), dim3(BT), 0, stream>>>(offs, ei, dinv, embh, x1h, NTOT);
    conv_csr2<<<dim3(nb), dim3(BT), 0, stream>>>(offs, ei, dinv, embh, x1h, outh, NTOT);

    // final v5: 2 edges per 16-lane group
    {
        long long groups = (E + 1) / 2;
        final_kernel<<<dim3((groups * 16 + BT - 1) / BT), dim3(BT), 0, stream>>>(
            up_e, ut_e, utag_e, (const float4*)src_feat, (const float4*)dst_feat,
            outh, (const float4*)W_src, (const float4*)b_src,
            (const float4*)W_dst, (const float4*)b_dst, out, E, NP, NT);
    }
}

// Round 7
// 453.441 us; speedup vs baseline: 2.0591x; 1.0408x over previous
//
#include <hip/hip_runtime.h>

#define DIM 64

__device__ __forceinline__ float bf2f(unsigned short u) {
    union { unsigned int i; float f; } v; v.i = ((unsigned int)u) << 16; return v.f;
}
__device__ __forceinline__ unsigned short f2bf(float f) {
    union { float f; unsigned int i; } v; v.f = f;
    unsigned int r = v.i + 0x7fff + ((v.i >> 16) & 1);   // RNE (no NaN inputs here)
    return (unsigned short)(r >> 16);
}
__device__ __forceinline__ float4 u2f4(ushort4 u) {
    float4 f; f.x = bf2f(u.x); f.y = bf2f(u.y); f.z = bf2f(u.z); f.w = bf2f(u.w);
    return f;
}
__device__ __forceinline__ ushort4 f2u4(float4 f) {
    ushort4 u; u.x = f2bf(f.x); u.y = f2bf(f.y); u.z = f2bf(f.z); u.w = f2bf(f.w);
    return u;
}
__device__ __forceinline__ float4 fma4(float4 a, float s, float4 c) {
    c.x = fmaf(a.x, s, c.x); c.y = fmaf(a.y, s, c.y);
    c.z = fmaf(a.z, s, c.z); c.w = fmaf(a.w, s, c.w);
    return c;
}

// ---- fused: degree count (first 3E threads) + emb fp32->bf16 convert ----
__global__ void deg_cvt_kernel(const int* __restrict__ d0, const int* __restrict__ d1,
                               const int* __restrict__ d2, int* __restrict__ degi,
                               const float4* __restrict__ e0, const float4* __restrict__ e1,
                               const float4* __restrict__ e2, ushort4* __restrict__ embh,
                               int NP, int NT, int NG, int E) {
    int i = blockIdx.x * blockDim.x + threadIdx.x;
    int degN = 3 * E;
    if (i < degN) {
        int g = i / E;
        int j = i - g * E;
        const int* dd = (g == 0) ? d0 : (g == 1) ? d1 : d2;
        int base = (g == 0) ? 0 : (g == 1) ? NP : NP + NT;
        atomicAdd(&degi[base + dd[j]], 1);
        return;
    }
    int i2 = i - degN;
    int np16 = NP * 16, nt16 = NT * 16, ng16 = NG * 16;
    if (i2 >= np16 + nt16 + ng16) return;
    const float4* s; int j;
    if (i2 < np16)              { s = e0; j = i2; }
    else if (i2 < np16 + nt16)  { s = e1; j = i2 - np16; }
    else                        { s = e2; j = i2 - np16 - nt16; }
    embh[i2] = f2u4(s[j]);
}

// ---- parallel scan, stage 1: per-block (256-elem) sums ----
__global__ void block_sums(const int* __restrict__ degi, int* __restrict__ bsum, int n) {
    int i = blockIdx.x * 256 + threadIdx.x;
    int v = (i < n) ? degi[i] : 0;
#pragma unroll
    for (int s = 1; s < 64; s <<= 1) v += __shfl_xor(v, s, 64);
    __shared__ int ws[4];
    if ((threadIdx.x & 63) == 0) ws[threadIdx.x >> 6] = v;
    __syncthreads();
    if (threadIdx.x == 0) bsum[blockIdx.x] = ws[0] + ws[1] + ws[2] + ws[3];
}

// ---- stage 2: exclusive scan of block sums (single block, nb <= 1024) ----
__global__ void scan_bsums(int* __restrict__ bsum, int nb) {
    int lane = threadIdx.x & 63, wid = threadIdx.x >> 6;
    int v = (threadIdx.x < nb) ? bsum[threadIdx.x] : 0;
    int x = v;
#pragma unroll
    for (int s = 1; s < 64; s <<= 1) {
        int y = __shfl_up(x, s, 64);
        if (lane >= s) x += y;
    }
    __shared__ int ws[16];
    if (lane == 63) ws[wid] = x;
    __syncthreads();
    int pre = 0;
    for (int w2 = 0; w2 < wid; ++w2) pre += ws[w2];
    if (threadIdx.x < nb) bsum[threadIdx.x] = pre + x - v;   // exclusive
}

// ---- stage 3: global exclusive offsets + cursor copy + dinv ----
__global__ void scatter_offs(const int* __restrict__ degi, const int* __restrict__ bpre,
                             int* __restrict__ offs, int* __restrict__ cur,
                             float* __restrict__ dinv, int n, int total) {
    int i = blockIdx.x * 256 + threadIdx.x;
    int lane = threadIdx.x & 63, wid = threadIdx.x >> 6;
    int v = (i < n) ? degi[i] : 0;
    int x = v;
#pragma unroll
    for (int s = 1; s < 64; s <<= 1) {
        int y = __shfl_up(x, s, 64);
        if (lane >= s) x += y;
    }
    __shared__ int ws[4];
    if (lane == 63) ws[wid] = x;
    __syncthreads();
    int pre = bpre[blockIdx.x];
    for (int w2 = 0; w2 < wid; ++w2) pre += ws[w2];
    if (i < n) {
        int e = pre + x - v;
        offs[i] = e; cur[i] = e;
        dinv[i] = (v > 0) ? rsqrtf((float)v) : 0.0f;
    }
    if (i == 0) offs[n] = total;
}

// ---- permute all 3E edges into dst-sorted CSR order (4 B src-index payload) ----
// XCD-range-partitioned: block b handles dst-range r = b&7 of graph/chunk c = b>>3.
__global__ void permute3_kernel(const int* __restrict__ up, const int* __restrict__ ut,
                                const int* __restrict__ ug, int* __restrict__ cur,
                                int* __restrict__ ei, int NP, int NT, int NG, int E,
                                int CP) {
    int r = blockIdx.x & 7;          // dst range (intended XCD)
    int c = blockIdx.x >> 3;         // chunk index across the 3 graphs
    int g = (c >= 2 * CP) ? 2 : (c >= CP) ? 1 : 0;
    int lc = c - g * CP;
    const int* edge = (g == 0) ? up : (g == 1) ? ut : ug;
    int nb = (g == 0) ? 0 : (g == 1) ? NP : NP + NT;
    int Ng = (g == 0) ? NP : (g == 1) ? NT : NG;
    int Q  = (Ng + 7) >> 3;
    int lo = r * Q;
    int hi = lo + Q; if (hi > Ng) hi = Ng;
    int base = lc * 2048 + threadIdx.x;
#pragma unroll
    for (int u = 0; u < 8; ++u) {
        int j = base + u * 256;
        if (j < E) {
            int t = edge[E + j];                     // dst (local id)
            if (t >= lo && t < hi) {
                int s = edge[j] + nb;                // src (global id)
                int p = atomicAdd(&cur[t + nb], 1);
                ei[p] = s;
            }
        }
    }
}

// ---- conv layer 1: x1[n] = dinv[n] * sum_in emb[s]*dinv[s]  (bf16 rows) ----
__global__ void conv_csr1(const int* __restrict__ offs, const int* __restrict__ ei,
                          const float* __restrict__ dinv,
                          const ushort4* __restrict__ xin, ushort4* __restrict__ xout, int N) {
    int gid = blockIdx.x * blockDim.x + threadIdx.x;
    int n = gid >> 4, l = gid & 15;
    if (n >= N) return;
    int beg = offs[n], end = offs[n + 1];
    float4 acc = {0.f, 0.f, 0.f, 0.f};
    int k = beg;
    for (; k + 3 < end; k += 4) {
        int s0 = ei[k], s1 = ei[k + 1], s2 = ei[k + 2], s3 = ei[k + 3];
        float w0 = dinv[s0], w1 = dinv[s1], w2 = dinv[s2], w3 = dinv[s3];
        ushort4 u0 = xin[(size_t)s0 * 16 + l];
        ushort4 u1 = xin[(size_t)s1 * 16 + l];
        ushort4 u2 = xin[(size_t)s2 * 16 + l];
        ushort4 u3 = xin[(size_t)s3 * 16 + l];
        acc = fma4(u2f4(u0), w0, acc);
        acc = fma4(u2f4(u1), w1, acc);
        acc = fma4(u2f4(u2), w2, acc);
        acc = fma4(u2f4(u3), w3, acc);
    }
    for (; k < end; ++k) {
        int s = ei[k];
        acc = fma4(u2f4(xin[(size_t)s * 16 + l]), dinv[s], acc);
    }
    float sc = dinv[n];
    float4 r; r.x = acc.x * sc; r.y = acc.y * sc; r.z = acc.z * sc; r.w = acc.w * sc;
    xout[(size_t)n * 16 + l] = f2u4(r);
}

// ---- conv layer 2 + epilogue: out[n] = (emb + x1 + dinv[n]*sum x1[s]*dinv[s]) / 3 ----
__global__ void conv_csr2(const int* __restrict__ offs, const int* __restrict__ ei,
                          const float* __restrict__ dinv,
                          const ushort4* __restrict__ emb, const ushort4* __restrict__ x1,
                          ushort4* __restrict__ out, int N) {
    int gid = blockIdx.x * blockDim.x + threadIdx.x;
    int n = gid >> 4, l = gid & 15;
    if (n >= N) return;
    int beg = offs[n], end = offs[n + 1];
    float4 acc = {0.f, 0.f, 0.f, 0.f};
    int k = beg;
    for (; k + 3 < end; k += 4) {
        int s0 = ei[k], s1 = ei[k + 1], s2 = ei[k + 2], s3 = ei[k + 3];
        float w0 = dinv[s0], w1 = dinv[s1], w2 = dinv[s2], w3 = dinv[s3];
        ushort4 u0 = x1[(size_t)s0 * 16 + l];
        ushort4 u1 = x1[(size_t)s1 * 16 + l];
        ushort4 u2 = x1[(size_t)s2 * 16 + l];
        ushort4 u3 = x1[(size_t)s3 * 16 + l];
        acc = fma4(u2f4(u0), w0, acc);
        acc = fma4(u2f4(u1), w1, acc);
        acc = fma4(u2f4(u2), w2, acc);
        acc = fma4(u2f4(u3), w3, acc);
    }
    for (; k < end; ++k) {
        int s = ei[k];
        acc = fma4(u2f4(x1[(size_t)s * 16 + l]), dinv[s], acc);
    }
    float sc = dinv[n];
    size_t idx = (size_t)n * 16 + l;
    float4 em = u2f4(emb[idx]), x = u2f4(x1[idx]);
    const float third = 1.0f / 3.0f;
    float4 o;
    o.x = (em.x + x.x + acc.x * sc) * third;
    o.y = (em.y + x.y + acc.y * sc) * third;
    o.z = (em.z + x.z + acc.z * sc) * third;
    o.w = (em.w + x.w + acc.w * sc) * third;
    out[idx] = f2u4(o);
}

// ---- final v6: 16-lane groups, JB=2, LDS-staged features (low-VGPR de-shfl) ----
// Ledger: r1 (shfl GEMM, VGPR 48, occ 44%) = 84us; r5 (reg-feature de-shfl,
// VGPR 104, occ 20%) = 119us. Need BOTH occupancy and few LDS ops. Fix: the
// 64 VGPRs of live feature registers move to LDS (512 B/group):
//   coalesced lane-striped load -> 4x ds_write_b32 -> GEMM reads group-uniform
//   ds_read_b128 (broadcast; 20-float padded stride -> conflict-free reads,
//   2-way-free writes). GEMM stays shfl-free and vmcnt-decoupled (weights +
//   features both on lgkm), gathers pinned above it with sched_barrier(0).
// LDS ops per 8-edge wave-iter: 32 weight b128 + 8 writes + 16 feature b128
// + 8 reduce = 64  (r1: ~88, r5 had reg pressure instead).
__global__ __launch_bounds__(256) void final_kernel(
        const int* __restrict__ up_e, const int* __restrict__ ut_e,
        const int* __restrict__ utag_e,
        const float* __restrict__ SF, const float* __restrict__ DF,
        const ushort4* __restrict__ O,
        const float4* __restrict__ W_s4, const float4* __restrict__ b_s4,
        const float4* __restrict__ W_d4, const float4* __restrict__ b_d4,
        float* __restrict__ out, int E, int NP, int NT) {
    __shared__ float4 LWs[256], LWd[256];
    __shared__ float LF[16][2][20], LG[16][2][20];   // [group][edge][16 + pad4]
    int tid = threadIdx.x;
    LWs[tid] = W_s4[tid];          // 16x16 float4 = full [16,64] weight matrix
    LWd[tid] = W_d4[tid];
    __syncthreads();

    int gid = blockIdx.x * blockDim.x + tid;
    int grp = gid >> 4;
    int l = gid & 15;
    int g = tid >> 4;              // group within block (0..15)
    int e0 = grp * 2;
    if (e0 >= E) return;
    int ec0 = e0;
    int ec1 = (e0 + 1 < E) ? (e0 + 1) : (E - 1);

    // ---- phase 0: coalesced feature loads (lane l holds feature l) ----
    float fA = SF[(size_t)ec0 * 16 + l];
    float fB = SF[(size_t)ec1 * 16 + l];
    float gA = DF[(size_t)ec0 * 16 + l];
    float gB = DF[(size_t)ec1 * 16 + l];
    float4 bsv = b_s4[l], bdv = b_d4[l];

    // ---- phase 1: edge indices ----
    int sp0 = up_e[ec0],              dp0 = up_e[E + ec0];
    int st0 = ut_e[ec0] + NP,         dt0 = ut_e[E + ec0] + NP;
    int sg0 = utag_e[ec0] + NP + NT,  dg0 = utag_e[E + ec0] + NP + NT;
    int sp1 = up_e[ec1],              dp1 = up_e[E + ec1];
    int st1 = ut_e[ec1] + NP,         dt1 = ut_e[E + ec1] + NP;
    int sg1 = utag_e[ec1] + NP + NT,  dg1 = utag_e[E + ec1] + NP + NT;

    // stage features to LDS (waits only the feature loads; group-private
    // region, wave-coherent via lgkmcnt -- no __syncthreads needed)
    LF[g][0][l] = fA;  LF[g][1][l] = fB;
    LG[g][0][l] = gA;  LG[g][1][l] = gB;

    // ---- phase 2: 12 O-row gathers (8B/lane, one 128B row per instr) ----
    ushort4 a00 = O[(size_t)sp0 * 16 + l];
    ushort4 a01 = O[(size_t)st0 * 16 + l];
    ushort4 a02 = O[(size_t)sg0 * 16 + l];
    ushort4 b00 = O[(size_t)dp0 * 16 + l];
    ushort4 b01 = O[(size_t)dt0 * 16 + l];
    ushort4 b02 = O[(size_t)dg0 * 16 + l];
    ushort4 a10 = O[(size_t)sp1 * 16 + l];
    ushort4 a11 = O[(size_t)st1 * 16 + l];
    ushort4 a12 = O[(size_t)sg1 * 16 + l];
    ushort4 b10 = O[(size_t)dp1 * 16 + l];
    ushort4 b11 = O[(size_t)dt1 * 16 + l];
    ushort4 b12 = O[(size_t)dg1 * 16 + l];
    __builtin_amdgcn_sched_barrier(0);   // pin gathers above the GEMM

    // ---- phase 3: feature GEMM, all operands on the lgkm counter ----
    const float4* F0p = (const float4*)LF[g][0];
    const float4* F1p = (const float4*)LF[g][1];
    const float4* G0p = (const float4*)LG[g][0];
    const float4* G1p = (const float4*)LG[g][1];
    float4 fs0 = bsv, fd0 = bdv, fs1 = bsv, fd1 = bdv;
#pragma unroll
    for (int kb = 0; kb < 4; ++kb) {
        float4 F0 = F0p[kb], F1 = F1p[kb];
        float4 G0 = G0p[kb], G1 = G1p[kb];
        float4 w0 = LWs[(kb * 4 + 0) * 16 + l];
        float4 w1 = LWs[(kb * 4 + 1) * 16 + l];
        float4 w2 = LWs[(kb * 4 + 2) * 16 + l];
        float4 w3 = LWs[(kb * 4 + 3) * 16 + l];
        float4 v0 = LWd[(kb * 4 + 0) * 16 + l];
        float4 v1 = LWd[(kb * 4 + 1) * 16 + l];
        float4 v2 = LWd[(kb * 4 + 2) * 16 + l];
        float4 v3 = LWd[(kb * 4 + 3) * 16 + l];
        fs0 = fma4(w0, F0.x, fs0); fs0 = fma4(w1, F0.y, fs0);
        fs0 = fma4(w2, F0.z, fs0); fs0 = fma4(w3, F0.w, fs0);
        fd0 = fma4(v0, G0.x, fd0); fd0 = fma4(v1, G0.y, fd0);
        fd0 = fma4(v2, G0.z, fd0); fd0 = fma4(v3, G0.w, fd0);
        fs1 = fma4(w0, F1.x, fs1); fs1 = fma4(w1, F1.y, fs1);
        fs1 = fma4(w2, F1.z, fs1); fs1 = fma4(w3, F1.w, fs1);
        fd1 = fma4(v0, G1.x, fd1); fd1 = fma4(v1, G1.y, fd1);
        fd1 = fma4(v2, G1.z, fd1); fd1 = fma4(v3, G1.w, fd1);
    }

    // ---- phase 4: epilogue (waits on gathers) ----
    const float third = 1.0f / 3.0f;
    {
        float4 vp = u2f4(a00), vt = u2f4(a01), vg = u2f4(a02);
        float4 P, Q;
        P.x = (vp.x + vt.x + vg.x) * third + fs0.x;
        P.y = (vp.y + vt.y + vg.y) * third + fs0.y;
        P.z = (vp.z + vt.z + vg.z) * third + fs0.z;
        P.w = (vp.w + vt.w + vg.w) * third + fs0.w;
        vp = u2f4(b00); vt = u2f4(b01); vg = u2f4(b02);
        Q.x = (vp.x + vt.x + vg.x) * third + fd0.x;
        Q.y = (vp.y + vt.y + vg.y) * third + fd0.y;
        Q.z = (vp.z + vt.z + vg.z) * third + fd0.z;
        Q.w = (vp.w + vt.w + vg.w) * third + fd0.w;
        float p = P.x * Q.x + P.y * Q.y + P.z * Q.z + P.w * Q.w;
        p += __shfl_xor(p, 8, 64);
        p += __shfl_xor(p, 4, 64);
        p += __shfl_xor(p, 2, 64);
        p += __shfl_xor(p, 1, 64);
        if (l == 0) out[e0] = p;
    }
    if (e0 + 1 < E) {
        float4 vp = u2f4(a10), vt = u2f4(a11), vg = u2f4(a12);
        float4 P, Q;
        P.x = (vp.x + vt.x + vg.x) * third + fs1.x;
        P.y = (vp.y + vt.y + vg.y) * third + fs1.y;
        P.z = (vp.z + vt.z + vg.z) * third + fs1.z;
        P.w = (vp.w + vt.w + vg.w) * third + fs1.w;
        vp = u2f4(b10); vt = u2f4(b11); vg = u2f4(b12);
        Q.x = (vp.x + vt.x + vg.x) * third + fd1.x;
        Q.y = (vp.y + vt.y + vg.y) * third + fd1.y;
        Q.z = (vp.z + vt.z + vg.z) * third + fd1.z;
        Q.w = (vp.w + vt.w + vg.w) * third + fd1.w;
        float p = P.x * Q.x + P.y * Q.y + P.z * Q.z + P.w * Q.w;
        p += __shfl_xor(p, 8, 64);
        p += __shfl_xor(p, 4, 64);
        p += __shfl_xor(p, 2, 64);
        p += __shfl_xor(p, 1, 64);
        if (l == 0) out[e0 + 1] = p;
    }
}

extern "C" void kernel_launch(void* const* d_in, const int* in_sizes, int n_in,
                              void* d_out, int out_size, void* d_ws, size_t ws_size,
                              hipStream_t stream) {
    const int*   up_e     = (const int*)d_in[0];
    const int*   ut_e     = (const int*)d_in[1];
    const int*   utag_e   = (const int*)d_in[2];
    const float* src_feat = (const float*)d_in[3];
    const float* dst_feat = (const float*)d_in[4];
    const float* up_emb   = (const float*)d_in[5];
    const float* ut_emb   = (const float*)d_in[6];
    const float* utag_emb = (const float*)d_in[7];
    const float* W_src    = (const float*)d_in[8];
    const float* b_src    = (const float*)d_in[9];
    const float* W_dst    = (const float*)d_in[10];
    const float* b_dst    = (const float*)d_in[11];
    float* out = (float*)d_out;

    const int E  = in_sizes[0] / 2;
    const int NP = in_sizes[5] / DIM;
    const int NT = in_sizes[6] / DIM;
    const int NG = in_sizes[7] / DIM;
    const int NTOT = NP + NT + NG;
    const int NB = (NTOT + 255) / 256;          // scan blocks

    // ---- workspace layout ----
    char* w = (char*)d_ws;
    int*  degi = (int*)w;                       w += (size_t)NTOT * 4;
    int*  offs = (int*)w;                       w += (size_t)(NTOT + 1) * 4;
    int*  cur  = (int*)w;                       w += (size_t)NTOT * 4;
    int*  bsum = (int*)w;                       w += (size_t)1024 * 4;
    float* dinv = (float*)w;                    w += (size_t)NTOT * 4;
    w = (char*)(((uintptr_t)w + 127) & ~(uintptr_t)127);
    int*  ei   = (int*)w;                       w += (size_t)3 * E * 4;
    w = (char*)(((uintptr_t)w + 127) & ~(uintptr_t)127);
    ushort4* embh = (ushort4*)w;                w += (size_t)NTOT * 16 * 8;   // bf16 emb
    ushort4* x1h  = (ushort4*)w;                w += (size_t)NTOT * 16 * 8;   // bf16 x1
    ushort4* outh = (ushort4*)w;                // bf16 aggregated node table

    const int BT = 256;

    hipMemsetAsync(degi, 0, (size_t)NTOT * 4, stream);

    // fused degree count + emb bf16 convert
    {
        long long tot = 3LL * E + (long long)NTOT * 16;
        deg_cvt_kernel<<<dim3((tot + BT - 1) / BT), dim3(BT), 0, stream>>>(
            up_e + E, ut_e + E, utag_e + E, degi,
            (const float4*)up_emb, (const float4*)ut_emb, (const float4*)utag_emb,
            embh, NP, NT, NG, E);
    }

    // global parallel exclusive scan over all nodes (+ dinv)
    block_sums<<<dim3(NB), dim3(BT), 0, stream>>>(degi, bsum, NTOT);
    scan_bsums<<<dim3(1), dim3(1024), 0, stream>>>(bsum, NB);
    scatter_offs<<<dim3(NB), dim3(BT), 0, stream>>>(degi, bsum, offs, cur, dinv, NTOT, 3 * E);

    // XCD-range-partitioned CSR build: (3 graphs x CP chunks) x (8 ranges)
    {
        int CP = (E + 2047) / 2048;             // chunks per graph (2048 edges each)
        permute3_kernel<<<dim3(8 * 3 * CP), dim3(BT), 0, stream>>>(
            up_e, ut_e, utag_e, cur, ei, NP, NT, NG, E, CP);
    }

    // conv layers over ALL nodes
    int nb = ((size_t)NTOT * 16 + BT - 1) / BT;
    conv_csr1<<<dim3(nb), dim3(BT), 0, stream>>>(offs, ei, dinv, embh, x1h, NTOT);
    conv_csr2<<<dim3(nb), dim3(BT), 0, stream>>>(offs, ei, dinv, embh, x1h, outh, NTOT);

    // final v6: 2 edges per 16-lane group, LDS-staged features
    {
        long long groups = (E + 1) / 2;
        final_kernel<<<dim3((groups * 16 + BT - 1) / BT), dim3(BT), 0, stream>>>(
            up_e, ut_e, utag_e, src_feat, dst_feat,
            outh, (const float4*)W_src, (const float4*)b_src,
            (const float4*)W_dst, (const float4*)b_dst, out, E, NP, NT);
    }
}

// Round 8
// 425.605 us; speedup vs baseline: 2.1938x; 1.0654x over previous
//
#include <hip/hip_runtime.h>

#define DIM 64

__device__ __forceinline__ float bf2f(unsigned short u) {
    union { unsigned int i; float f; } v; v.i = ((unsigned int)u) << 16; return v.f;
}
__device__ __forceinline__ unsigned short f2bf(float f) {
    union { float f; unsigned int i; } v; v.f = f;
    unsigned int r = v.i + 0x7fff + ((v.i >> 16) & 1);   // RNE (no NaN inputs here)
    return (unsigned short)(r >> 16);
}
__device__ __forceinline__ float4 u2f4(ushort4 u) {
    float4 f; f.x = bf2f(u.x); f.y = bf2f(u.y); f.z = bf2f(u.z); f.w = bf2f(u.w);
    return f;
}
__device__ __forceinline__ ushort4 f2u4(float4 f) {
    ushort4 u; u.x = f2bf(f.x); u.y = f2bf(f.y); u.z = f2bf(f.z); u.w = f2bf(f.w);
    return u;
}
__device__ __forceinline__ float4 fma4(float4 a, float s, float4 c) {
    c.x = fmaf(a.x, s, c.x); c.y = fmaf(a.y, s, c.y);
    c.z = fmaf(a.z, s, c.z); c.w = fmaf(a.w, s, c.w);
    return c;
}
__device__ __forceinline__ float4 add4(float4 a, float4 b) {
    float4 r; r.x = a.x + b.x; r.y = a.y + b.y; r.z = a.z + b.z; r.w = a.w + b.w;
    return r;
}

// ---- fused: degree count (first 3E threads) + emb fp32->bf16 convert ----
__global__ void deg_cvt_kernel(const int* __restrict__ d0, const int* __restrict__ d1,
                               const int* __restrict__ d2, int* __restrict__ degi,
                               const float4* __restrict__ e0, const float4* __restrict__ e1,
                               const float4* __restrict__ e2, ushort4* __restrict__ embh,
                               int NP, int NT, int NG, int E) {
    int i = blockIdx.x * blockDim.x + threadIdx.x;
    int degN = 3 * E;
    if (i < degN) {
        int g = i / E;
        int j = i - g * E;
        const int* dd = (g == 0) ? d0 : (g == 1) ? d1 : d2;
        int base = (g == 0) ? 0 : (g == 1) ? NP : NP + NT;
        atomicAdd(&degi[base + dd[j]], 1);
        return;
    }
    int i2 = i - degN;
    int np16 = NP * 16, nt16 = NT * 16, ng16 = NG * 16;
    if (i2 >= np16 + nt16 + ng16) return;
    const float4* s; int j;
    if (i2 < np16)              { s = e0; j = i2; }
    else if (i2 < np16 + nt16)  { s = e1; j = i2 - np16; }
    else                        { s = e2; j = i2 - np16 - nt16; }
    embh[i2] = f2u4(s[j]);
}

// ---- parallel scan, stage 1: per-block (256-elem) sums ----
__global__ void block_sums(const int* __restrict__ degi, int* __restrict__ bsum, int n) {
    int i = blockIdx.x * 256 + threadIdx.x;
    int v = (i < n) ? degi[i] : 0;
#pragma unroll
    for (int s = 1; s < 64; s <<= 1) v += __shfl_xor(v, s, 64);
    __shared__ int ws[4];
    if ((threadIdx.x & 63) == 0) ws[threadIdx.x >> 6] = v;
    __syncthreads();
    if (threadIdx.x == 0) bsum[blockIdx.x] = ws[0] + ws[1] + ws[2] + ws[3];
}

// ---- stage 2: exclusive scan of block sums (single block, nb <= 1024) ----
__global__ void scan_bsums(int* __restrict__ bsum, int nb) {
    int lane = threadIdx.x & 63, wid = threadIdx.x >> 6;
    int v = (threadIdx.x < nb) ? bsum[threadIdx.x] : 0;
    int x = v;
#pragma unroll
    for (int s = 1; s < 64; s <<= 1) {
        int y = __shfl_up(x, s, 64);
        if (lane >= s) x += y;
    }
    __shared__ int ws[16];
    if (lane == 63) ws[wid] = x;
    __syncthreads();
    int pre = 0;
    for (int w2 = 0; w2 < wid; ++w2) pre += ws[w2];
    if (threadIdx.x < nb) bsum[threadIdx.x] = pre + x - v;   // exclusive
}

// ---- stage 3: global exclusive offsets + cursor copy + dinv ----
__global__ void scatter_offs(const int* __restrict__ degi, const int* __restrict__ bpre,
                             int* __restrict__ offs, int* __restrict__ cur,
                             float* __restrict__ dinv, int n, int total) {
    int i = blockIdx.x * 256 + threadIdx.x;
    int lane = threadIdx.x & 63, wid = threadIdx.x >> 6;
    int v = (i < n) ? degi[i] : 0;
    int x = v;
#pragma unroll
    for (int s = 1; s < 64; s <<= 1) {
        int y = __shfl_up(x, s, 64);
        if (lane >= s) x += y;
    }
    __shared__ int ws[4];
    if (lane == 63) ws[wid] = x;
    __syncthreads();
    int pre = bpre[blockIdx.x];
    for (int w2 = 0; w2 < wid; ++w2) pre += ws[w2];
    if (i < n) {
        int e = pre + x - v;
        offs[i] = e; cur[i] = e;
        dinv[i] = (v > 0) ? rsqrtf((float)v) : 0.0f;
    }
    if (i == 0) offs[n] = total;
}

// ---- permute all 3E edges into dst-sorted CSR order (4 B src-index payload) ----
// XCD-range-partitioned: block b handles dst-range r = b&7 of graph/chunk c = b>>3.
__global__ void permute3_kernel(const int* __restrict__ up, const int* __restrict__ ut,
                                const int* __restrict__ ug, int* __restrict__ cur,
                                int* __restrict__ ei, int NP, int NT, int NG, int E,
                                int CP) {
    int r = blockIdx.x & 7;          // dst range (intended XCD)
    int c = blockIdx.x >> 3;         // chunk index across the 3 graphs
    int g = (c >= 2 * CP) ? 2 : (c >= CP) ? 1 : 0;
    int lc = c - g * CP;
    const int* edge = (g == 0) ? up : (g == 1) ? ut : ug;
    int nb = (g == 0) ? 0 : (g == 1) ? NP : NP + NT;
    int Ng = (g == 0) ? NP : (g == 1) ? NT : NG;
    int Q  = (Ng + 7) >> 3;
    int lo = r * Q;
    int hi = lo + Q; if (hi > Ng) hi = Ng;
    int base = lc * 2048 + threadIdx.x;
#pragma unroll
    for (int u = 0; u < 8; ++u) {
        int j = base + u * 256;
        if (j < E) {
            int t = edge[E + j];                     // dst (local id)
            if (t >= lo && t < hi) {
                int s = edge[j] + nb;                // src (global id)
                int p = atomicAdd(&cur[t + nb], 1);
                ei[p] = s;
            }
        }
    }
}

// ---- conv layer 1: x1[n] = dinv[n] * sum_in emb[s]*dinv[s]  (bf16 rows) ----
// v7: 4 independent accumulators break the per-component FMA dep chain
// (was: one acc through 16 sequential FMAs per 4-edge iteration).
__global__ void conv_csr1(const int* __restrict__ offs, const int* __restrict__ ei,
                          const float* __restrict__ dinv,
                          const ushort4* __restrict__ xin, ushort4* __restrict__ xout, int N) {
    int gid = blockIdx.x * blockDim.x + threadIdx.x;
    int n = gid >> 4, l = gid & 15;
    if (n >= N) return;
    int beg = offs[n], end = offs[n + 1];
    float4 a0 = {0.f, 0.f, 0.f, 0.f}, a1 = a0, a2 = a0, a3 = a0;
    int k = beg;
    for (; k + 3 < end; k += 4) {
        int s0 = ei[k], s1 = ei[k + 1], s2 = ei[k + 2], s3 = ei[k + 3];
        float w0 = dinv[s0], w1 = dinv[s1], w2 = dinv[s2], w3 = dinv[s3];
        ushort4 u0 = xin[(size_t)s0 * 16 + l];
        ushort4 u1 = xin[(size_t)s1 * 16 + l];
        ushort4 u2 = xin[(size_t)s2 * 16 + l];
        ushort4 u3 = xin[(size_t)s3 * 16 + l];
        a0 = fma4(u2f4(u0), w0, a0);
        a1 = fma4(u2f4(u1), w1, a1);
        a2 = fma4(u2f4(u2), w2, a2);
        a3 = fma4(u2f4(u3), w3, a3);
    }
    for (; k < end; ++k) {
        int s = ei[k];
        a0 = fma4(u2f4(xin[(size_t)s * 16 + l]), dinv[s], a0);
    }
    float4 acc = add4(add4(a0, a1), add4(a2, a3));
    float sc = dinv[n];
    float4 r; r.x = acc.x * sc; r.y = acc.y * sc; r.z = acc.z * sc; r.w = acc.w * sc;
    xout[(size_t)n * 16 + l] = f2u4(r);
}

// ---- conv layer 2 + epilogue: out[n] = (emb + x1 + dinv[n]*sum x1[s]*dinv[s]) / 3 ----
__global__ void conv_csr2(const int* __restrict__ offs, const int* __restrict__ ei,
                          const float* __restrict__ dinv,
                          const ushort4* __restrict__ emb, const ushort4* __restrict__ x1,
                          ushort4* __restrict__ out, int N) {
    int gid = blockIdx.x * blockDim.x + threadIdx.x;
    int n = gid >> 4, l = gid & 15;
    if (n >= N) return;
    int beg = offs[n], end = offs[n + 1];
    float4 a0 = {0.f, 0.f, 0.f, 0.f}, a1 = a0, a2 = a0, a3 = a0;
    int k = beg;
    for (; k + 3 < end; k += 4) {
        int s0 = ei[k], s1 = ei[k + 1], s2 = ei[k + 2], s3 = ei[k + 3];
        float w0 = dinv[s0], w1 = dinv[s1], w2 = dinv[s2], w3 = dinv[s3];
        ushort4 u0 = x1[(size_t)s0 * 16 + l];
        ushort4 u1 = x1[(size_t)s1 * 16 + l];
        ushort4 u2 = x1[(size_t)s2 * 16 + l];
        ushort4 u3 = x1[(size_t)s3 * 16 + l];
        a0 = fma4(u2f4(u0), w0, a0);
        a1 = fma4(u2f4(u1), w1, a1);
        a2 = fma4(u2f4(u2), w2, a2);
        a3 = fma4(u2f4(u3), w3, a3);
    }
    for (; k < end; ++k) {
        int s = ei[k];
        a0 = fma4(u2f4(x1[(size_t)s * 16 + l]), dinv[s], a0);
    }
    float4 acc = add4(add4(a0, a1), add4(a2, a3));
    float sc = dinv[n];
    size_t idx = (size_t)n * 16 + l;
    float4 em = u2f4(emb[idx]), x = u2f4(x1[idx]);
    const float third = 1.0f / 3.0f;
    float4 o;
    o.x = (em.x + x.x + acc.x * sc) * third;
    o.y = (em.y + x.y + acc.y * sc) * third;
    o.z = (em.z + x.z + acc.z * sc) * third;
    o.w = (em.w + x.w + acc.w * sc) * third;
    out[idx] = f2u4(o);
}

// ---- final (round-1 proven version, 84-85 us, VGPR 48, occ ~44%) ----
// 4 edges per 16-lane group; weights in LDS (lgkm counter, decoupled from the
// gather vmcnt queue); loads phase-ordered. Ledger of failed replacements:
// r4 wave-per-edge (250us, latency-serial), r5 reg-features (119us, occ 20%),
// r6 LDS-features (100us, occ 20% + bank conflicts). The VGPR-48/occ-44%
// configuration beats all lower-LDS-op variants -- occupancy dominates.
__global__ void final_kernel(const int* __restrict__ up_e, const int* __restrict__ ut_e,
                             const int* __restrict__ utag_e,
                             const float* __restrict__ src_feat, const float* __restrict__ dst_feat,
                             const ushort4* __restrict__ O,
                             const float4* __restrict__ W_s4, const float4* __restrict__ b_s4,
                             const float4* __restrict__ W_d4, const float4* __restrict__ b_d4,
                             float* __restrict__ out, int E, int NP, int NT) {
    __shared__ float4 LWs[256], LWd[256];
    int tid = threadIdx.x;
    LWs[tid] = W_s4[tid];          // 16x16 float4 = full [16,64] weight matrix
    LWd[tid] = W_d4[tid];
    __syncthreads();

    int gid = blockIdx.x * blockDim.x + tid;
    int grp = gid >> 4;
    int l = gid & 15;
    int e0 = grp * 4;
    if (e0 >= E) return;
    int lane = tid & 63;
    int gbase = lane & 48;

    // ---- phase 0: edge indices + features + biases (issued FIRST) ----
    int sp[4], dp[4], st[4], dt[4], sg[4], dg[4];
    float fsc[4], fdc[4];
#pragma unroll
    for (int j = 0; j < 4; ++j) {
        int e = e0 + j; if (e > E - 1) e = E - 1;
        sp[j] = up_e[e];              dp[j] = up_e[E + e];
        st[j] = ut_e[e] + NP;         dt[j] = ut_e[E + e] + NP;
        sg[j] = utag_e[e] + NP + NT;  dg[j] = utag_e[E + e] + NP + NT;
        fsc[j] = src_feat[(size_t)e * 16 + l];
        fdc[j] = dst_feat[(size_t)e * 16 + l];
    }
    float4 bsv = b_s4[l], bdv = b_d4[l];

    // ---- phase 1: the 24 random O-row gathers ----
    ushort4 as[4][3], bs[4][3];
#pragma unroll
    for (int j = 0; j < 4; ++j) {
        as[j][0] = O[(size_t)sp[j] * 16 + l];
        as[j][1] = O[(size_t)st[j] * 16 + l];
        as[j][2] = O[(size_t)sg[j] * 16 + l];
        bs[j][0] = O[(size_t)dp[j] * 16 + l];
        bs[j][1] = O[(size_t)dt[j] * 16 + l];
        bs[j][2] = O[(size_t)dg[j] * 16 + l];
    }

    // ---- phase 2: f32 feature GEMM from LDS weights (overlaps gathers) ----
    float4 fs[4], fd[4];
#pragma unroll
    for (int j = 0; j < 4; ++j) { fs[j] = bsv; fd[j] = bdv; }

#pragma unroll
    for (int k = 0; k < 16; ++k) {
        float4 ws = LWs[k * 16 + l];
        float4 wd = LWd[k * 16 + l];
#pragma unroll
        for (int j = 0; j < 4; ++j) {
            float a = __shfl(fsc[j], gbase + k, 64);
            float c = __shfl(fdc[j], gbase + k, 64);
            fs[j] = fma4(ws, a, fs[j]);
            fd[j] = fma4(wd, c, fd[j]);
        }
    }

    // ---- phase 3: epilogue (waits on gathers) ----
    const float third = 1.0f / 3.0f;
    float prod[4];
#pragma unroll
    for (int j = 0; j < 4; ++j) {
        float4 vp = u2f4(as[j][0]), vt = u2f4(as[j][1]), vg = u2f4(as[j][2]);
        float4 P, Q;
        P.x = (vp.x + vt.x + vg.x) * third + fs[j].x;
        P.y = (vp.y + vt.y + vg.y) * third + fs[j].y;
        P.z = (vp.z + vt.z + vg.z) * third + fs[j].z;
        P.w = (vp.w + vt.w + vg.w) * third + fs[j].w;
        vp = u2f4(bs[j][0]); vt = u2f4(bs[j][1]); vg = u2f4(bs[j][2]);
        Q.x = (vp.x + vt.x + vg.x) * third + fd[j].x;
        Q.y = (vp.y + vt.y + vg.y) * third + fd[j].y;
        Q.z = (vp.z + vt.z + vg.z) * third + fd[j].z;
        Q.w = (vp.w + vt.w + vg.w) * third + fd[j].w;
        float p = P.x * Q.x + P.y * Q.y + P.z * Q.z + P.w * Q.w;
        p += __shfl_xor(p, 8, 64);
        p += __shfl_xor(p, 4, 64);
        p += __shfl_xor(p, 2, 64);
        p += __shfl_xor(p, 1, 64);
        prod[j] = p;
    }
    if (l == 0) {
#pragma unroll
        for (int j = 0; j < 4; ++j)
            if (e0 + j < E) out[e0 + j] = prod[j];
    }
}

extern "C" void kernel_launch(void* const* d_in, const int* in_sizes, int n_in,
                              void* d_out, int out_size, void* d_ws, size_t ws_size,
                              hipStream_t stream) {
    const int*   up_e     = (const int*)d_in[0];
    const int*   ut_e     = (const int*)d_in[1];
    const int*   utag_e   = (const int*)d_in[2];
    const float* src_feat = (const float*)d_in[3];
    const float* dst_feat = (const float*)d_in[4];
    const float* up_emb   = (const float*)d_in[5];
    const float* ut_emb   = (const float*)d_in[6];
    const float* utag_emb = (const float*)d_in[7];
    const float* W_src    = (const float*)d_in[8];
    const float* b_src    = (const float*)d_in[9];
    const float* W_dst    = (const float*)d_in[10];
    const float* b_dst    = (const float*)d_in[11];
    float* out = (float*)d_out;

    const int E  = in_sizes[0] / 2;
    const int NP = in_sizes[5] / DIM;
    const int NT = in_sizes[6] / DIM;
    const int NG = in_sizes[7] / DIM;
    const int NTOT = NP + NT + NG;
    const int NB = (NTOT + 255) / 256;          // scan blocks

    // ---- workspace layout ----
    char* w = (char*)d_ws;
    int*  degi = (int*)w;                       w += (size_t)NTOT * 4;
    int*  offs = (int*)w;                       w += (size_t)(NTOT + 1) * 4;
    int*  cur  = (int*)w;                       w += (size_t)NTOT * 4;
    int*  bsum = (int*)w;                       w += (size_t)1024 * 4;
    float* dinv = (float*)w;                    w += (size_t)NTOT * 4;
    w = (char*)(((uintptr_t)w + 127) & ~(uintptr_t)127);
    int*  ei   = (int*)w;                       w += (size_t)3 * E * 4;
    w = (char*)(((uintptr_t)w + 127) & ~(uintptr_t)127);
    ushort4* embh = (ushort4*)w;                w += (size_t)NTOT * 16 * 8;   // bf16 emb
    ushort4* x1h  = (ushort4*)w;                w += (size_t)NTOT * 16 * 8;   // bf16 x1
    ushort4* outh = (ushort4*)w;                // bf16 aggregated node table

    const int BT = 256;

    hipMemsetAsync(degi, 0, (size_t)NTOT * 4, stream);

    // fused degree count + emb bf16 convert
    {
        long long tot = 3LL * E + (long long)NTOT * 16;
        deg_cvt_kernel<<<dim3((tot + BT - 1) / BT), dim3(BT), 0, stream>>>(
            up_e + E, ut_e + E, utag_e + E, degi,
            (const float4*)up_emb, (const float4*)ut_emb, (const float4*)utag_emb,
            embh, NP, NT, NG, E);
    }

    // global parallel exclusive scan over all nodes (+ dinv)
    block_sums<<<dim3(NB), dim3(BT), 0, stream>>>(degi, bsum, NTOT);
    scan_bsums<<<dim3(1), dim3(1024), 0, stream>>>(bsum, NB);
    scatter_offs<<<dim3(NB), dim3(BT), 0, stream>>>(degi, bsum, offs, cur, dinv, NTOT, 3 * E);

    // XCD-range-partitioned CSR build: (3 graphs x CP chunks) x (8 ranges)
    {
        int CP = (E + 2047) / 2048;             // chunks per graph (2048 edges each)
        permute3_kernel<<<dim3(8 * 3 * CP), dim3(BT), 0, stream>>>(
            up_e, ut_e, utag_e, cur, ei, NP, NT, NG, E, CP);
    }

    // conv layers over ALL nodes
    int nb = ((size_t)NTOT * 16 + BT - 1) / BT;
    conv_csr1<<<dim3(nb), dim3(BT), 0, stream>>>(offs, ei, dinv, embh, x1h, NTOT);
    conv_csr2<<<dim3(nb), dim3(BT), 0, stream>>>(offs, ei, dinv, embh, x1h, outh, NTOT);

    // final: 4 edges per 16-lane group (round-1 configuration)
    long long groups = (E + 3) / 4;
    final_kernel<<<dim3((groups * 16 + BT - 1) / BT), dim3(BT), 0, stream>>>(
        up_e, ut_e, utag_e, src_feat, dst_feat, outh,
        (const float4*)W_src, (const float4*)b_src,
        (const float4*)W_dst, (const float4*)b_dst, out, E, NP, NT);
}

// Round 9
// 384.702 us; speedup vs baseline: 2.4270x; 1.1063x over previous
//
#include <hip/hip_runtime.h>

#define DIM 64
#define RNG 8        // node ranges per graph (LDS-owned)
#define CHK 8        // edge chunks per graph
#define LDSH 14336   // LDS histogram/cursor capacity (ints); ceil(110000/8)=13750 fits

__device__ __forceinline__ float bf2f(unsigned short u) {
    union { unsigned int i; float f; } v; v.i = ((unsigned int)u) << 16; return v.f;
}
__device__ __forceinline__ unsigned short f2bf(float f) {
    union { float f; unsigned int i; } v; v.f = f;
    unsigned int r = v.i + 0x7fff + ((v.i >> 16) & 1);   // RNE (no NaN inputs here)
    return (unsigned short)(r >> 16);
}
__device__ __forceinline__ float4 u2f4(ushort4 u) {
    float4 f; f.x = bf2f(u.x); f.y = bf2f(u.y); f.z = bf2f(u.z); f.w = bf2f(u.w);
    return f;
}
__device__ __forceinline__ ushort4 f2u4(float4 f) {
    ushort4 u; u.x = f2bf(f.x); u.y = f2bf(f.y); u.z = f2bf(f.z); u.w = f2bf(f.w);
    return u;
}
__device__ __forceinline__ float4 fma4(float4 a, float s, float4 c) {
    c.x = fmaf(a.x, s, c.x); c.y = fmaf(a.y, s, c.y);
    c.z = fmaf(a.z, s, c.z); c.w = fmaf(a.w, s, c.w);
    return c;
}
__device__ __forceinline__ float4 add4(float4 a, float4 b) {
    float4 r; r.x = a.x + b.x; r.y = a.y + b.y; r.z = a.z + b.z; r.w = a.w + b.w;
    return r;
}

// ---- deg (LDS histograms, ZERO global atomics) + emb fp32->bf16 convert ----
// Round-7 counters: 1.5M device-scope atomicAdds = memory-side RMW (per-XCD L2s
// non-coherent -> atomics execute at the common LLC point; 46MB write-through,
// 83us at 3.7% VALU). Fix: block (g,r,c) histograms chunk c's dsts falling in
// node-range r into private LDS (LDS atomics are on-CU), then PLAIN-stores to
// hist[c] -- exactly one writer per (c,node) cell. Conversion blocks ride along.
__global__ __launch_bounds__(1024) void deg_cvt_kernel(
        const int* __restrict__ up, const int* __restrict__ ut,
        const int* __restrict__ ug, int* __restrict__ hist,
        const float4* __restrict__ e0, const float4* __restrict__ e1,
        const float4* __restrict__ e2, ushort4* __restrict__ embh,
        int NP, int NT, int NG, int NTOT, int E) {
    __shared__ int lh[LDSH];
    int b = blockIdx.x;
    const int HB = 3 * RNG * CHK;
    if (b < HB) {
        int c  = b & (CHK - 1);
        int gr = b >> 3;             // CHK==8
        int g  = gr >> 3;            // RNG==8
        int r  = gr & (RNG - 1);
        const int* edge = (g == 0) ? up : (g == 1) ? ut : ug;
        int nb = (g == 0) ? 0 : (g == 1) ? NP : NP + NT;
        int Ng = (g == 0) ? NP : (g == 1) ? NT : NG;
        int Q  = (Ng + RNG - 1) / RNG;
        int lo = r * Q;
        int hi = lo + Q; if (hi > Ng) hi = Ng;
        int nloc = hi - lo;
        for (int t = threadIdx.x; t < nloc; t += 1024) lh[t] = 0;
        __syncthreads();
        int CE = (E + CHK - 1) / CHK;
        int jb = c * CE, je = jb + CE; if (je > E) je = E;
        for (int j = jb + threadIdx.x; j < je; j += 1024) {
            int t = edge[E + j];                         // dst (local id)
            if (t >= lo && t < hi) atomicAdd(&lh[t - lo], 1);
        }
        __syncthreads();
        for (int t = threadIdx.x; t < nloc; t += 1024)
            hist[(size_t)c * NTOT + nb + lo + t] = lh[t];
        return;
    }
    // ---- emb conversion blocks ----
    int i2 = (b - HB) * 1024 + threadIdx.x;
    int np16 = NP * 16, nt16 = NT * 16, ng16 = NG * 16;
    if (i2 >= np16 + nt16 + ng16) return;
    const float4* s; int j;
    if (i2 < np16)              { s = e0; j = i2; }
    else if (i2 < np16 + nt16)  { s = e1; j = i2 - np16; }
    else                        { s = e2; j = i2 - np16 - nt16; }
    embh[i2] = f2u4(s[j]);
}

// ---- parallel scan, stage 1: per-block (256-elem) sums over summed chunk-hists ----
__global__ void block_sums(const int* __restrict__ hist, int* __restrict__ bsum,
                           int n) {
    int i = blockIdx.x * 256 + threadIdx.x;
    int v = 0;
    if (i < n) {
#pragma unroll
        for (int c = 0; c < CHK; ++c) v += hist[(size_t)c * n + i];
    }
#pragma unroll
    for (int s = 1; s < 64; s <<= 1) v += __shfl_xor(v, s, 64);
    __shared__ int ws[4];
    if ((threadIdx.x & 63) == 0) ws[threadIdx.x >> 6] = v;
    __syncthreads();
    if (threadIdx.x == 0) bsum[blockIdx.x] = ws[0] + ws[1] + ws[2] + ws[3];
}

// ---- stage 2: exclusive scan of block sums (single block, nb <= 1024) ----
__global__ void scan_bsums(int* __restrict__ bsum, int nb) {
    int lane = threadIdx.x & 63, wid = threadIdx.x >> 6;
    int v = (threadIdx.x < nb) ? bsum[threadIdx.x] : 0;
    int x = v;
#pragma unroll
    for (int s = 1; s < 64; s <<= 1) {
        int y = __shfl_up(x, s, 64);
        if (lane >= s) x += y;
    }
    __shared__ int ws[16];
    if (lane == 63) ws[wid] = x;
    __syncthreads();
    int pre = 0;
    for (int w2 = 0; w2 < wid; ++w2) pre += ws[w2];
    if (threadIdx.x < nb) bsum[threadIdx.x] = pre + x - v;   // exclusive
}

// ---- stage 3: global exclusive offsets + dinv (no cursor copy needed) ----
__global__ void scatter_offs(const int* __restrict__ hist, const int* __restrict__ bpre,
                             int* __restrict__ offs, float* __restrict__ dinv,
                             int n, int total) {
    int i = blockIdx.x * 256 + threadIdx.x;
    int lane = threadIdx.x & 63, wid = threadIdx.x >> 6;
    int v = 0;
    if (i < n) {
#pragma unroll
        for (int c = 0; c < CHK; ++c) v += hist[(size_t)c * n + i];
    }
    int x = v;
#pragma unroll
    for (int s = 1; s < 64; s <<= 1) {
        int y = __shfl_up(x, s, 64);
        if (lane >= s) x += y;
    }
    __shared__ int ws[4];
    if (lane == 63) ws[wid] = x;
    __syncthreads();
    int pre = bpre[blockIdx.x];
    for (int w2 = 0; w2 < wid; ++w2) pre += ws[w2];
    if (i < n) {
        int e = pre + x - v;
        offs[i] = e;
        dinv[i] = (v > 0) ? rsqrtf((float)v) : 0.0f;
    }
    if (i == 0) offs[n] = total;
}

// ---- permute into dst-sorted CSR order (ZERO global atomics) ----
// Block (g,r,c): LDS cursors for node-range r, initialized to
// offs[n] + sum_{c'<c} hist[c'][n]  (the chunk histograms ARE the 2D prefix).
// Slots provably unique; ei writes span one contiguous region per block.
__global__ __launch_bounds__(1024) void permute3_kernel(
        const int* __restrict__ up, const int* __restrict__ ut,
        const int* __restrict__ ug, const int* __restrict__ offs,
        const int* __restrict__ hist, int* __restrict__ ei,
        int NP, int NT, int NG, int NTOT, int E) {
    __shared__ int lcur[LDSH];
    int b = blockIdx.x;
    int c  = b & (CHK - 1);
    int gr = b >> 3;
    int g  = gr >> 3;
    int r  = gr & (RNG - 1);
    const int* edge = (g == 0) ? up : (g == 1) ? ut : ug;
    int nb = (g == 0) ? 0 : (g == 1) ? NP : NP + NT;
    int Ng = (g == 0) ? NP : (g == 1) ? NT : NG;
    int Q  = (Ng + RNG - 1) / RNG;
    int lo = r * Q;
    int hi = lo + Q; if (hi > Ng) hi = Ng;
    int nloc = hi - lo;
    for (int t = threadIdx.x; t < nloc; t += 1024) {
        int base = offs[nb + lo + t];
        for (int c2 = 0; c2 < c; ++c2)
            base += hist[(size_t)c2 * NTOT + nb + lo + t];
        lcur[t] = base;
    }
    __syncthreads();
    int CE = (E + CHK - 1) / CHK;
    int jb = c * CE, je = jb + CE; if (je > E) je = E;
    for (int j = jb + threadIdx.x; j < je; j += 1024) {
        int t = edge[E + j];                             // dst (local id)
        if (t >= lo && t < hi) {
            int p = atomicAdd(&lcur[t - lo], 1);         // LDS atomic (on-CU)
            ei[p] = edge[j] + nb;                        // global src id
        }
    }
}

// ---- conv layer 1: x1[n] = dinv[n] * sum_in emb[s]*dinv[s]  (bf16 rows) ----
// 4 independent accumulators break the per-component FMA dep chain.
__global__ void conv_csr1(const int* __restrict__ offs, const int* __restrict__ ei,
                          const float* __restrict__ dinv,
                          const ushort4* __restrict__ xin, ushort4* __restrict__ xout, int N) {
    int gid = blockIdx.x * blockDim.x + threadIdx.x;
    int n = gid >> 4, l = gid & 15;
    if (n >= N) return;
    int beg = offs[n], end = offs[n + 1];
    float4 a0 = {0.f, 0.f, 0.f, 0.f}, a1 = a0, a2 = a0, a3 = a0;
    int k = beg;
    for (; k + 3 < end; k += 4) {
        int s0 = ei[k], s1 = ei[k + 1], s2 = ei[k + 2], s3 = ei[k + 3];
        float w0 = dinv[s0], w1 = dinv[s1], w2 = dinv[s2], w3 = dinv[s3];
        ushort4 u0 = xin[(size_t)s0 * 16 + l];
        ushort4 u1 = xin[(size_t)s1 * 16 + l];
        ushort4 u2 = xin[(size_t)s2 * 16 + l];
        ushort4 u3 = xin[(size_t)s3 * 16 + l];
        a0 = fma4(u2f4(u0), w0, a0);
        a1 = fma4(u2f4(u1), w1, a1);
        a2 = fma4(u2f4(u2), w2, a2);
        a3 = fma4(u2f4(u3), w3, a3);
    }
    for (; k < end; ++k) {
        int s = ei[k];
        a0 = fma4(u2f4(xin[(size_t)s * 16 + l]), dinv[s], a0);
    }
    float4 acc = add4(add4(a0, a1), add4(a2, a3));
    float sc = dinv[n];
    float4 r; r.x = acc.x * sc; r.y = acc.y * sc; r.z = acc.z * sc; r.w = acc.w * sc;
    xout[(size_t)n * 16 + l] = f2u4(r);
}

// ---- conv layer 2 + epilogue: out[n] = (emb + x1 + dinv[n]*sum x1[s]*dinv[s]) / 3 ----
__global__ void conv_csr2(const int* __restrict__ offs, const int* __restrict__ ei,
                          const float* __restrict__ dinv,
                          const ushort4* __restrict__ emb, const ushort4* __restrict__ x1,
                          ushort4* __restrict__ out, int N) {
    int gid = blockIdx.x * blockDim.x + threadIdx.x;
    int n = gid >> 4, l = gid & 15;
    if (n >= N) return;
    int beg = offs[n], end = offs[n + 1];
    float4 a0 = {0.f, 0.f, 0.f, 0.f}, a1 = a0, a2 = a0, a3 = a0;
    int k = beg;
    for (; k + 3 < end; k += 4) {
        int s0 = ei[k], s1 = ei[k + 1], s2 = ei[k + 2], s3 = ei[k + 3];
        float w0 = dinv[s0], w1 = dinv[s1], w2 = dinv[s2], w3 = dinv[s3];
        ushort4 u0 = x1[(size_t)s0 * 16 + l];
        ushort4 u1 = x1[(size_t)s1 * 16 + l];
        ushort4 u2 = x1[(size_t)s2 * 16 + l];
        ushort4 u3 = x1[(size_t)s3 * 16 + l];
        a0 = fma4(u2f4(u0), w0, a0);
        a1 = fma4(u2f4(u1), w1, a1);
        a2 = fma4(u2f4(u2), w2, a2);
        a3 = fma4(u2f4(u3), w3, a3);
    }
    for (; k < end; ++k) {
        int s = ei[k];
        a0 = fma4(u2f4(x1[(size_t)s * 16 + l]), dinv[s], a0);
    }
    float4 acc = add4(add4(a0, a1), add4(a2, a3));
    float sc = dinv[n];
    size_t idx = (size_t)n * 16 + l;
    float4 em = u2f4(emb[idx]), x = u2f4(x1[idx]);
    const float third = 1.0f / 3.0f;
    float4 o;
    o.x = (em.x + x.x + acc.x * sc) * third;
    o.y = (em.y + x.y + acc.y * sc) * third;
    o.z = (em.z + x.z + acc.z * sc) * third;
    o.w = (em.w + x.w + acc.w * sc) * third;
    out[idx] = f2u4(o);
}

// ---- final (round-1 proven version: VGPR 48, occ ~44%, ~84us) ----
// 4 edges per 16-lane group; weights in LDS; loads phase-ordered. Failed
// replacements (ledger): wave-per-edge 250us, reg-features 119us,
// LDS-features 100us -- occupancy dominates LDS-op count for this kernel.
__global__ void final_kernel(const int* __restrict__ up_e, const int* __restrict__ ut_e,
                             const int* __restrict__ utag_e,
                             const float* __restrict__ src_feat, const float* __restrict__ dst_feat,
                             const ushort4* __restrict__ O,
                             const float4* __restrict__ W_s4, const float4* __restrict__ b_s4,
                             const float4* __restrict__ W_d4, const float4* __restrict__ b_d4,
                             float* __restrict__ out, int E, int NP, int NT) {
    __shared__ float4 LWs[256], LWd[256];
    int tid = threadIdx.x;
    LWs[tid] = W_s4[tid];          // 16x16 float4 = full [16,64] weight matrix
    LWd[tid] = W_d4[tid];
    __syncthreads();

    int gid = blockIdx.x * blockDim.x + tid;
    int grp = gid >> 4;
    int l = gid & 15;
    int e0 = grp * 4;
    if (e0 >= E) return;
    int lane = tid & 63;
    int gbase = lane & 48;

    // ---- phase 0: edge indices + features + biases (issued FIRST) ----
    int sp[4], dp[4], st[4], dt[4], sg[4], dg[4];
    float fsc[4], fdc[4];
#pragma unroll
    for (int j = 0; j < 4; ++j) {
        int e = e0 + j; if (e > E - 1) e = E - 1;
        sp[j] = up_e[e];              dp[j] = up_e[E + e];
        st[j] = ut_e[e] + NP;         dt[j] = ut_e[E + e] + NP;
        sg[j] = utag_e[e] + NP + NT;  dg[j] = utag_e[E + e] + NP + NT;
        fsc[j] = src_feat[(size_t)e * 16 + l];
        fdc[j] = dst_feat[(size_t)e * 16 + l];
    }
    float4 bsv = b_s4[l], bdv = b_d4[l];

    // ---- phase 1: the 24 random O-row gathers ----
    ushort4 as[4][3], bs[4][3];
#pragma unroll
    for (int j = 0; j < 4; ++j) {
        as[j][0] = O[(size_t)sp[j] * 16 + l];
        as[j][1] = O[(size_t)st[j] * 16 + l];
        as[j][2] = O[(size_t)sg[j] * 16 + l];
        bs[j][0] = O[(size_t)dp[j] * 16 + l];
        bs[j][1] = O[(size_t)dt[j] * 16 + l];
        bs[j][2] = O[(size_t)dg[j] * 16 + l];
    }

    // ---- phase 2: f32 feature GEMM from LDS weights (overlaps gathers) ----
    float4 fs[4], fd[4];
#pragma unroll
    for (int j = 0; j < 4; ++j) { fs[j] = bsv; fd[j] = bdv; }

#pragma unroll
    for (int k = 0; k < 16; ++k) {
        float4 ws = LWs[k * 16 + l];
        float4 wd = LWd[k * 16 + l];
#pragma unroll
        for (int j = 0; j < 4; ++j) {
            float a = __shfl(fsc[j], gbase + k, 64);
            float c = __shfl(fdc[j], gbase + k, 64);
            fs[j] = fma4(ws, a, fs[j]);
            fd[j] = fma4(wd, c, fd[j]);
        }
    }

    // ---- phase 3: epilogue (waits on gathers) ----
    const float third = 1.0f / 3.0f;
    float prod[4];
#pragma unroll
    for (int j = 0; j < 4; ++j) {
        float4 vp = u2f4(as[j][0]), vt = u2f4(as[j][1]), vg = u2f4(as[j][2]);
        float4 P, Q;
        P.x = (vp.x + vt.x + vg.x) * third + fs[j].x;
        P.y = (vp.y + vt.y + vg.y) * third + fs[j].y;
        P.z = (vp.z + vt.z + vg.z) * third + fs[j].z;
        P.w = (vp.w + vt.w + vg.w) * third + fs[j].w;
        vp = u2f4(bs[j][0]); vt = u2f4(bs[j][1]); vg = u2f4(bs[j][2]);
        Q.x = (vp.x + vt.x + vg.x) * third + fd[j].x;
        Q.y = (vp.y + vt.y + vg.y) * third + fd[j].y;
        Q.z = (vp.z + vt.z + vg.z) * third + fd[j].z;
        Q.w = (vp.w + vt.w + vg.w) * third + fd[j].w;
        float p = P.x * Q.x + P.y * Q.y + P.z * Q.z + P.w * Q.w;
        p += __shfl_xor(p, 8, 64);
        p += __shfl_xor(p, 4, 64);
        p += __shfl_xor(p, 2, 64);
        p += __shfl_xor(p, 1, 64);
        prod[j] = p;
    }
    if (l == 0) {
#pragma unroll
        for (int j = 0; j < 4; ++j)
            if (e0 + j < E) out[e0 + j] = prod[j];
    }
}

extern "C" void kernel_launch(void* const* d_in, const int* in_sizes, int n_in,
                              void* d_out, int out_size, void* d_ws, size_t ws_size,
                              hipStream_t stream) {
    const int*   up_e     = (const int*)d_in[0];
    const int*   ut_e     = (const int*)d_in[1];
    const int*   utag_e   = (const int*)d_in[2];
    const float* src_feat = (const float*)d_in[3];
    const float* dst_feat = (const float*)d_in[4];
    const float* up_emb   = (const float*)d_in[5];
    const float* ut_emb   = (const float*)d_in[6];
    const float* utag_emb = (const float*)d_in[7];
    const float* W_src    = (const float*)d_in[8];
    const float* b_src    = (const float*)d_in[9];
    const float* W_dst    = (const float*)d_in[10];
    const float* b_dst    = (const float*)d_in[11];
    float* out = (float*)d_out;

    const int E  = in_sizes[0] / 2;
    const int NP = in_sizes[5] / DIM;
    const int NT = in_sizes[6] / DIM;
    const int NG = in_sizes[7] / DIM;
    const int NTOT = NP + NT + NG;
    const int NB = (NTOT + 255) / 256;          // scan blocks

    // ---- workspace layout ----
    char* w = (char*)d_ws;
    int*  hist = (int*)w;                       w += (size_t)CHK * NTOT * 4;  // chunk hists
    int*  offs = (int*)w;                       w += (size_t)(NTOT + 1) * 4;
    int*  bsum = (int*)w;                       w += (size_t)1024 * 4;
    float* dinv = (float*)w;                    w += (size_t)NTOT * 4;
    w = (char*)(((uintptr_t)w + 127) & ~(uintptr_t)127);
    int*  ei   = (int*)w;                       w += (size_t)3 * E * 4;
    w = (char*)(((uintptr_t)w + 127) & ~(uintptr_t)127);
    ushort4* embh = (ushort4*)w;                w += (size_t)NTOT * 16 * 8;   // bf16 emb
    ushort4* x1h  = (ushort4*)w;                w += (size_t)NTOT * 16 * 8;   // bf16 x1
    ushort4* outh = (ushort4*)w;                // bf16 aggregated node table

    const int BT = 256;
    const int HB = 3 * RNG * CHK;               // histogram blocks

    // deg histograms (atomic-free) + emb bf16 convert, fused
    {
        int convBlocks = (NTOT * 16 + 1023) / 1024;
        deg_cvt_kernel<<<dim3(HB + convBlocks), dim3(1024), 0, stream>>>(
            up_e, ut_e, utag_e, hist,
            (const float4*)up_emb, (const float4*)ut_emb, (const float4*)utag_emb,
            embh, NP, NT, NG, NTOT, E);
    }

    // global parallel exclusive scan over summed chunk-hists (+ dinv)
    block_sums<<<dim3(NB), dim3(BT), 0, stream>>>(hist, bsum, NTOT);
    scan_bsums<<<dim3(1), dim3(1024), 0, stream>>>(bsum, NB);
    scatter_offs<<<dim3(NB), dim3(BT), 0, stream>>>(hist, bsum, offs, dinv, NTOT, 3 * E);

    // CSR build: LDS cursors seeded from offs + chunk-hist prefix (atomic-free)
    permute3_kernel<<<dim3(HB), dim3(1024), 0, stream>>>(
        up_e, ut_e, utag_e, offs, hist, ei, NP, NT, NG, NTOT, E);

    // conv layers over ALL nodes
    int nb = ((size_t)NTOT * 16 + BT - 1) / BT;
    conv_csr1<<<dim3(nb), dim3(BT), 0, stream>>>(offs, ei, dinv, embh, x1h, NTOT);
    conv_csr2<<<dim3(nb), dim3(BT), 0, stream>>>(offs, ei, dinv, embh, x1h, outh, NTOT);

    // final: 4 edges per 16-lane group (round-1 configuration)
    long long groups = (E + 3) / 4;
    final_kernel<<<dim3((groups * 16 + BT - 1) / BT), dim3(BT), 0, stream>>>(
        up_e, ut_e, utag_e, src_feat, dst_feat, outh,
        (const float4*)W_src, (const float4*)b_src,
        (const float4*)W_dst, (const float4*)b_dst, out, E, NP, NT);
}

// Round 10
// 369.607 us; speedup vs baseline: 2.5261x; 1.0408x over previous
//
#include <hip/hip_runtime.h>

#define DIM 64
#define RNG 8        // node ranges per graph (LDS-owned)
#define CHK 8        // edge chunks per graph
#define LDSH 14336   // LDS histogram/cursor capacity (ints); ceil(110000/8)=13750 fits

__device__ __forceinline__ float bf2f(unsigned short u) {
    union { unsigned int i; float f; } v; v.i = ((unsigned int)u) << 16; return v.f;
}
__device__ __forceinline__ unsigned short f2bf(float f) {
    union { float f; unsigned int i; } v; v.f = f;
    unsigned int r = v.i + 0x7fff + ((v.i >> 16) & 1);   // RNE (no NaN inputs here)
    return (unsigned short)(r >> 16);
}
__device__ __forceinline__ float4 u2f4(ushort4 u) {
    float4 f; f.x = bf2f(u.x); f.y = bf2f(u.y); f.z = bf2f(u.z); f.w = bf2f(u.w);
    return f;
}
__device__ __forceinline__ ushort4 f2u4(float4 f) {
    ushort4 u; u.x = f2bf(f.x); u.y = f2bf(f.y); u.z = f2bf(f.z); u.w = f2bf(f.w);
    return u;
}
__device__ __forceinline__ float4 fma4(float4 a, float s, float4 c) {
    c.x = fmaf(a.x, s, c.x); c.y = fmaf(a.y, s, c.y);
    c.z = fmaf(a.z, s, c.z); c.w = fmaf(a.w, s, c.w);
    return c;
}
__device__ __forceinline__ float4 add4(float4 a, float4 b) {
    float4 r; r.x = a.x + b.x; r.y = a.y + b.y; r.z = a.z + b.z; r.w = a.w + b.w;
    return r;
}

// ---- deg (LDS histograms, ZERO global atomics) + emb fp32->bf16 convert ----
// Block (g,r,c) histograms chunk c's dsts falling in node-range r into private
// LDS (on-CU atomics), then PLAIN-stores to hist[c] -- one writer per cell.
// hist writes are contiguous per block -> full lines, no XCD-sharing issue.
__global__ __launch_bounds__(1024) void deg_cvt_kernel(
        const int* __restrict__ up, const int* __restrict__ ut,
        const int* __restrict__ ug, int* __restrict__ hist,
        const float4* __restrict__ e0, const float4* __restrict__ e1,
        const float4* __restrict__ e2, ushort4* __restrict__ embh,
        int NP, int NT, int NG, int NTOT, int E) {
    __shared__ int lh[LDSH];
    int b = blockIdx.x;
    const int HB = 3 * RNG * CHK;
    if (b < HB) {
        int c  = b & (CHK - 1);
        int gr = b >> 3;             // CHK==8
        int g  = gr >> 3;            // RNG==8
        int r  = gr & (RNG - 1);
        const int* edge = (g == 0) ? up : (g == 1) ? ut : ug;
        int nb = (g == 0) ? 0 : (g == 1) ? NP : NP + NT;
        int Ng = (g == 0) ? NP : (g == 1) ? NT : NG;
        int Q  = (Ng + RNG - 1) / RNG;
        int lo = r * Q;
        int hi = lo + Q; if (hi > Ng) hi = Ng;
        int nloc = hi - lo;
        for (int t = threadIdx.x; t < nloc; t += 1024) lh[t] = 0;
        __syncthreads();
        int CE = (E + CHK - 1) / CHK;
        int jb = c * CE, je = jb + CE; if (je > E) je = E;
        for (int j = jb + threadIdx.x; j < je; j += 1024) {
            int t = edge[E + j];                         // dst (local id)
            if (t >= lo && t < hi) atomicAdd(&lh[t - lo], 1);
        }
        __syncthreads();
        for (int t = threadIdx.x; t < nloc; t += 1024)
            hist[(size_t)c * NTOT + nb + lo + t] = lh[t];
        return;
    }
    // ---- emb conversion blocks ----
    int i2 = (b - HB) * 1024 + threadIdx.x;
    int np16 = NP * 16, nt16 = NT * 16, ng16 = NG * 16;
    if (i2 >= np16 + nt16 + ng16) return;
    const float4* s; int j;
    if (i2 < np16)              { s = e0; j = i2; }
    else if (i2 < np16 + nt16)  { s = e1; j = i2 - np16; }
    else                        { s = e2; j = i2 - np16 - nt16; }
    embh[i2] = f2u4(s[j]);
}

// ---- parallel scan, stage 1: per-block (256-elem) sums over summed chunk-hists ----
__global__ void block_sums(const int* __restrict__ hist, int* __restrict__ bsum,
                           int n) {
    int i = blockIdx.x * 256 + threadIdx.x;
    int v = 0;
    if (i < n) {
#pragma unroll
        for (int c = 0; c < CHK; ++c) v += hist[(size_t)c * n + i];
    }
#pragma unroll
    for (int s = 1; s < 64; s <<= 1) v += __shfl_xor(v, s, 64);
    __shared__ int ws[4];
    if ((threadIdx.x & 63) == 0) ws[threadIdx.x >> 6] = v;
    __syncthreads();
    if (threadIdx.x == 0) bsum[blockIdx.x] = ws[0] + ws[1] + ws[2] + ws[3];
}

// ---- stage 2: exclusive scan of block sums (single block, nb <= 1024) ----
__global__ void scan_bsums(int* __restrict__ bsum, int nb) {
    int lane = threadIdx.x & 63, wid = threadIdx.x >> 6;
    int v = (threadIdx.x < nb) ? bsum[threadIdx.x] : 0;
    int x = v;
#pragma unroll
    for (int s = 1; s < 64; s <<= 1) {
        int y = __shfl_up(x, s, 64);
        if (lane >= s) x += y;
    }
    __shared__ int ws[16];
    if (lane == 63) ws[wid] = x;
    __syncthreads();
    int pre = 0;
    for (int w2 = 0; w2 < wid; ++w2) pre += ws[w2];
    if (threadIdx.x < nb) bsum[threadIdx.x] = pre + x - v;   // exclusive
}

// ---- stage 3: global exclusive offsets + dinv ----
__global__ void scatter_offs(const int* __restrict__ hist, const int* __restrict__ bpre,
                             int* __restrict__ offs, float* __restrict__ dinv,
                             int n, int total) {
    int i = blockIdx.x * 256 + threadIdx.x;
    int lane = threadIdx.x & 63, wid = threadIdx.x >> 6;
    int v = 0;
    if (i < n) {
#pragma unroll
        for (int c = 0; c < CHK; ++c) v += hist[(size_t)c * n + i];
    }
    int x = v;
#pragma unroll
    for (int s = 1; s < 64; s <<= 1) {
        int y = __shfl_up(x, s, 64);
        if (lane >= s) x += y;
    }
    __shared__ int ws[4];
    if (lane == 63) ws[wid] = x;
    __syncthreads();
    int pre = bpre[blockIdx.x];
    for (int w2 = 0; w2 < wid; ++w2) pre += ws[w2];
    if (i < n) {
        int e = pre + x - v;
        offs[i] = e;
        dinv[i] = (v > 0) ? rsqrtf((float)v) : 0.0f;
    }
    if (i == 0) offs[n] = total;
}

// ---- permute into dst-sorted CSR order (ZERO global atomics) ----
// Block (g,r,c): LDS cursors for node-range r seeded from offs + chunk-hist
// prefix. XCD-ALIGNED DECODE (round-8 post-mortem): b = c*24 + gr, and since
// 24 % 8 == 0, b % 8 == gr % 8 -- ALL 8 chunks of one (g,r) land on the SAME
// XCD (round-robin dispatch). r8's decode (c = b&7) spread them over 8 XCDs
// interleaving 4B writes into the same ~250KB ei window -> every 64B line
// dirtied by 8 L2s -> 43MB partial-line writebacks for a 6MB ei. Now each ei
// line is assembled in one XCD's L2 and written back once, full.
__global__ __launch_bounds__(1024) void permute3_kernel(
        const int* __restrict__ up, const int* __restrict__ ut,
        const int* __restrict__ ug, const int* __restrict__ offs,
        const int* __restrict__ hist, int* __restrict__ ei,
        int NP, int NT, int NG, int NTOT, int E) {
    __shared__ int lcur[LDSH];
    int b = blockIdx.x;
    int c  = b / 24;                 // chunk (0..CHK-1); 24 = 3*RNG (g,r) pairs
    int gr = b - c * 24;             // (g,r); b%8 == gr%8 -> XCD-aligned
    int g  = gr >> 3;
    int r  = gr & (RNG - 1);
    const int* edge = (g == 0) ? up : (g == 1) ? ut : ug;
    int nb = (g == 0) ? 0 : (g == 1) ? NP : NP + NT;
    int Ng = (g == 0) ? NP : (g == 1) ? NT : NG;
    int Q  = (Ng + RNG - 1) / RNG;
    int lo = r * Q;
    int hi = lo + Q; if (hi > Ng) hi = Ng;
    int nloc = hi - lo;
    for (int t = threadIdx.x; t < nloc; t += 1024) {
        int base = offs[nb + lo + t];
        for (int c2 = 0; c2 < c; ++c2)
            base += hist[(size_t)c2 * NTOT + nb + lo + t];
        lcur[t] = base;
    }
    __syncthreads();
    int CE = (E + CHK - 1) / CHK;
    int jb = c * CE, je = jb + CE; if (je > E) je = E;
    for (int j = jb + threadIdx.x; j < je; j += 1024) {
        int t = edge[E + j];                             // dst (local id)
        if (t >= lo && t < hi) {
            int p = atomicAdd(&lcur[t - lo], 1);         // LDS atomic (on-CU)
            ei[p] = edge[j] + nb;                        // global src id
        }
    }
}

// ---- conv layer 1: x1[n] = dinv[n] * sum_in emb[s]*dinv[s]  (bf16 rows) ----
// 4 independent accumulators break the per-component FMA dep chain.
__global__ void conv_csr1(const int* __restrict__ offs, const int* __restrict__ ei,
                          const float* __restrict__ dinv,
                          const ushort4* __restrict__ xin, ushort4* __restrict__ xout, int N) {
    int gid = blockIdx.x * blockDim.x + threadIdx.x;
    int n = gid >> 4, l = gid & 15;
    if (n >= N) return;
    int beg = offs[n], end = offs[n + 1];
    float4 a0 = {0.f, 0.f, 0.f, 0.f}, a1 = a0, a2 = a0, a3 = a0;
    int k = beg;
    for (; k + 3 < end; k += 4) {
        int s0 = ei[k], s1 = ei[k + 1], s2 = ei[k + 2], s3 = ei[k + 3];
        float w0 = dinv[s0], w1 = dinv[s1], w2 = dinv[s2], w3 = dinv[s3];
        ushort4 u0 = xin[(size_t)s0 * 16 + l];
        ushort4 u1 = xin[(size_t)s1 * 16 + l];
        ushort4 u2 = xin[(size_t)s2 * 16 + l];
        ushort4 u3 = xin[(size_t)s3 * 16 + l];
        a0 = fma4(u2f4(u0), w0, a0);
        a1 = fma4(u2f4(u1), w1, a1);
        a2 = fma4(u2f4(u2), w2, a2);
        a3 = fma4(u2f4(u3), w3, a3);
    }
    for (; k < end; ++k) {
        int s = ei[k];
        a0 = fma4(u2f4(xin[(size_t)s * 16 + l]), dinv[s], a0);
    }
    float4 acc = add4(add4(a0, a1), add4(a2, a3));
    float sc = dinv[n];
    float4 r; r.x = acc.x * sc; r.y = acc.y * sc; r.z = acc.z * sc; r.w = acc.w * sc;
    xout[(size_t)n * 16 + l] = f2u4(r);
}

// ---- conv layer 2 + epilogue: out[n] = (emb + x1 + dinv[n]*sum x1[s]*dinv[s]) / 3 ----
__global__ void conv_csr2(const int* __restrict__ offs, const int* __restrict__ ei,
                          const float* __restrict__ dinv,
                          const ushort4* __restrict__ emb, const ushort4* __restrict__ x1,
                          ushort4* __restrict__ out, int N) {
    int gid = blockIdx.x * blockDim.x + threadIdx.x;
    int n = gid >> 4, l = gid & 15;
    if (n >= N) return;
    int beg = offs[n], end = offs[n + 1];
    float4 a0 = {0.f, 0.f, 0.f, 0.f}, a1 = a0, a2 = a0, a3 = a0;
    int k = beg;
    for (; k + 3 < end; k += 4) {
        int s0 = ei[k], s1 = ei[k + 1], s2 = ei[k + 2], s3 = ei[k + 3];
        float w0 = dinv[s0], w1 = dinv[s1], w2 = dinv[s2], w3 = dinv[s3];
        ushort4 u0 = x1[(size_t)s0 * 16 + l];
        ushort4 u1 = x1[(size_t)s1 * 16 + l];
        ushort4 u2 = x1[(size_t)s2 * 16 + l];
        ushort4 u3 = x1[(size_t)s3 * 16 + l];
        a0 = fma4(u2f4(u0), w0, a0);
        a1 = fma4(u2f4(u1), w1, a1);
        a2 = fma4(u2f4(u2), w2, a2);
        a3 = fma4(u2f4(u3), w3, a3);
    }
    for (; k < end; ++k) {
        int s = ei[k];
        a0 = fma4(u2f4(x1[(size_t)s * 16 + l]), dinv[s], a0);
    }
    float4 acc = add4(add4(a0, a1), add4(a2, a3));
    float sc = dinv[n];
    size_t idx = (size_t)n * 16 + l;
    float4 em = u2f4(emb[idx]), x = u2f4(x1[idx]);
    const float third = 1.0f / 3.0f;
    float4 o;
    o.x = (em.x + x.x + acc.x * sc) * third;
    o.y = (em.y + x.y + acc.y * sc) * third;
    o.z = (em.z + x.z + acc.z * sc) * third;
    o.w = (em.w + x.w + acc.w * sc) * third;
    out[idx] = f2u4(o);
}

// ---- final (round-1 proven version: VGPR 48, occ ~44%, ~84us) ----
// 4 edges per 16-lane group; weights in LDS; loads phase-ordered. Failed
// replacements (ledger): wave-per-edge 250us, reg-features 119us,
// LDS-features 100us -- occupancy dominates LDS-op count for this kernel.
__global__ void final_kernel(const int* __restrict__ up_e, const int* __restrict__ ut_e,
                             const int* __restrict__ utag_e,
                             const float* __restrict__ src_feat, const float* __restrict__ dst_feat,
                             const ushort4* __restrict__ O,
                             const float4* __restrict__ W_s4, const float4* __restrict__ b_s4,
                             const float4* __restrict__ W_d4, const float4* __restrict__ b_d4,
                             float* __restrict__ out, int E, int NP, int NT) {
    __shared__ float4 LWs[256], LWd[256];
    int tid = threadIdx.x;
    LWs[tid] = W_s4[tid];          // 16x16 float4 = full [16,64] weight matrix
    LWd[tid] = W_d4[tid];
    __syncthreads();

    int gid = blockIdx.x * blockDim.x + tid;
    int grp = gid >> 4;
    int l = gid & 15;
    int e0 = grp * 4;
    if (e0 >= E) return;
    int lane = tid & 63;
    int gbase = lane & 48;

    // ---- phase 0: edge indices + features + biases (issued FIRST) ----
    int sp[4], dp[4], st[4], dt[4], sg[4], dg[4];
    float fsc[4], fdc[4];
#pragma unroll
    for (int j = 0; j < 4; ++j) {
        int e = e0 + j; if (e > E - 1) e = E - 1;
        sp[j] = up_e[e];              dp[j] = up_e[E + e];
        st[j] = ut_e[e] + NP;         dt[j] = ut_e[E + e] + NP;
        sg[j] = utag_e[e] + NP + NT;  dg[j] = utag_e[E + e] + NP + NT;
        fsc[j] = src_feat[(size_t)e * 16 + l];
        fdc[j] = dst_feat[(size_t)e * 16 + l];
    }
    float4 bsv = b_s4[l], bdv = b_d4[l];

    // ---- phase 1: the 24 random O-row gathers ----
    ushort4 as[4][3], bs[4][3];
#pragma unroll
    for (int j = 0; j < 4; ++j) {
        as[j][0] = O[(size_t)sp[j] * 16 + l];
        as[j][1] = O[(size_t)st[j] * 16 + l];
        as[j][2] = O[(size_t)sg[j] * 16 + l];
        bs[j][0] = O[(size_t)dp[j] * 16 + l];
        bs[j][1] = O[(size_t)dt[j] * 16 + l];
        bs[j][2] = O[(size_t)dg[j] * 16 + l];
    }

    // ---- phase 2: f32 feature GEMM from LDS weights (overlaps gathers) ----
    float4 fs[4], fd[4];
#pragma unroll
    for (int j = 0; j < 4; ++j) { fs[j] = bsv; fd[j] = bdv; }

#pragma unroll
    for (int k = 0; k < 16; ++k) {
        float4 ws = LWs[k * 16 + l];
        float4 wd = LWd[k * 16 + l];
#pragma unroll
        for (int j = 0; j < 4; ++j) {
            float a = __shfl(fsc[j], gbase + k, 64);
            float c = __shfl(fdc[j], gbase + k, 64);
            fs[j] = fma4(ws, a, fs[j]);
            fd[j] = fma4(wd, c, fd[j]);
        }
    }

    // ---- phase 3: epilogue (waits on gathers) ----
    const float third = 1.0f / 3.0f;
    float prod[4];
#pragma unroll
    for (int j = 0; j < 4; ++j) {
        float4 vp = u2f4(as[j][0]), vt = u2f4(as[j][1]), vg = u2f4(as[j][2]);
        float4 P, Q;
        P.x = (vp.x + vt.x + vg.x) * third + fs[j].x;
        P.y = (vp.y + vt.y + vg.y) * third + fs[j].y;
        P.z = (vp.z + vt.z + vg.z) * third + fs[j].z;
        P.w = (vp.w + vt.w + vg.w) * third + fs[j].w;
        vp = u2f4(bs[j][0]); vt = u2f4(bs[j][1]); vg = u2f4(bs[j][2]);
        Q.x = (vp.x + vt.x + vg.x) * third + fd[j].x;
        Q.y = (vp.y + vt.y + vg.y) * third + fd[j].y;
        Q.z = (vp.z + vt.z + vg.z) * third + fd[j].z;
        Q.w = (vp.w + vt.w + vg.w) * third + fd[j].w;
        float p = P.x * Q.x + P.y * Q.y + P.z * Q.z + P.w * Q.w;
        p += __shfl_xor(p, 8, 64);
        p += __shfl_xor(p, 4, 64);
        p += __shfl_xor(p, 2, 64);
        p += __shfl_xor(p, 1, 64);
        prod[j] = p;
    }
    if (l == 0) {
#pragma unroll
        for (int j = 0; j < 4; ++j)
            if (e0 + j < E) out[e0 + j] = prod[j];
    }
}

extern "C" void kernel_launch(void* const* d_in, const int* in_sizes, int n_in,
                              void* d_out, int out_size, void* d_ws, size_t ws_size,
                              hipStream_t stream) {
    const int*   up_e     = (const int*)d_in[0];
    const int*   ut_e     = (const int*)d_in[1];
    const int*   utag_e   = (const int*)d_in[2];
    const float* src_feat = (const float*)d_in[3];
    const float* dst_feat = (const float*)d_in[4];
    const float* up_emb   = (const float*)d_in[5];
    const float* ut_emb   = (const float*)d_in[6];
    const float* utag_emb = (const float*)d_in[7];
    const float* W_src    = (const float*)d_in[8];
    const float* b_src    = (const float*)d_in[9];
    const float* W_dst    = (const float*)d_in[10];
    const float* b_dst    = (const float*)d_in[11];
    float* out = (float*)d_out;

    const int E  = in_sizes[0] / 2;
    const int NP = in_sizes[5] / DIM;
    const int NT = in_sizes[6] / DIM;
    const int NG = in_sizes[7] / DIM;
    const int NTOT = NP + NT + NG;
    const int NB = (NTOT + 255) / 256;          // scan blocks

    // ---- workspace layout ----
    char* w = (char*)d_ws;
    int*  hist = (int*)w;                       w += (size_t)CHK * NTOT * 4;  // chunk hists
    int*  offs = (int*)w;                       w += (size_t)(NTOT + 1) * 4;
    int*  bsum = (int*)w;                       w += (size_t)1024 * 4;
    float* dinv = (float*)w;                    w += (size_t)NTOT * 4;
    w = (char*)(((uintptr_t)w + 127) & ~(uintptr_t)127);
    int*  ei   = (int*)w;                       w += (size_t)3 * E * 4;
    w = (char*)(((uintptr_t)w + 127) & ~(uintptr_t)127);
    ushort4* embh = (ushort4*)w;                w += (size_t)NTOT * 16 * 8;   // bf16 emb
    ushort4* x1h  = (ushort4*)w;                w += (size_t)NTOT * 16 * 8;   // bf16 x1
    ushort4* outh = (ushort4*)w;                // bf16 aggregated node table

    const int BT = 256;
    const int HB = 3 * RNG * CHK;               // histogram blocks

    // deg histograms (atomic-free) + emb bf16 convert, fused
    {
        int convBlocks = (NTOT * 16 + 1023) / 1024;
        deg_cvt_kernel<<<dim3(HB + convBlocks), dim3(1024), 0, stream>>>(
            up_e, ut_e, utag_e, hist,
            (const float4*)up_emb, (const float4*)ut_emb, (const float4*)utag_emb,
            embh, NP, NT, NG, NTOT, E);
    }

    // global parallel exclusive scan over summed chunk-hists (+ dinv)
    block_sums<<<dim3(NB), dim3(BT), 0, stream>>>(hist, bsum, NTOT);
    scan_bsums<<<dim3(1), dim3(1024), 0, stream>>>(bsum, NB);
    scatter_offs<<<dim3(NB), dim3(BT), 0, stream>>>(hist, bsum, offs, dinv, NTOT, 3 * E);

    // CSR build: LDS cursors, XCD-aligned chunk blocks (b%8 == gr%8)
    permute3_kernel<<<dim3(HB), dim3(1024), 0, stream>>>(
        up_e, ut_e, utag_e, offs, hist, ei, NP, NT, NG, NTOT, E);

    // conv layers over ALL nodes
    int nb = ((size_t)NTOT * 16 + BT - 1) / BT;
    conv_csr1<<<dim3(nb), dim3(BT), 0, stream>>>(offs, ei, dinv, embh, x1h, NTOT);
    conv_csr2<<<dim3(nb), dim3(BT), 0, stream>>>(offs, ei, dinv, embh, x1h, outh, NTOT);

    // final: 4 edges per 16-lane group (round-1 configuration)
    long long groups = (E + 3) / 4;
    final_kernel<<<dim3((groups * 16 + BT - 1) / BT), dim3(BT), 0, stream>>>(
        up_e, ut_e, utag_e, src_feat, dst_feat, outh,
        (const float4*)W_src, (const float4*)b_src,
        (const float4*)W_dst, (const float4*)b_dst, out, E, NP, NT);
}

// Round 11
// 332.592 us; speedup vs baseline: 2.8073x; 1.1113x over previous
//
#include <hip/hip_runtime.h>

#define DIM 64
#define RNG 8        // node ranges per graph (LDS-owned)
#define CHK 16       // edge chunks per graph (r10: 8->16, 384 blocks ~1.5/CU)
#define LDSH 14336   // LDS histogram/cursor capacity (ints); ceil(110000/8)=13750 fits

__device__ __forceinline__ float bf2f(unsigned short u) {
    union { unsigned int i; float f; } v; v.i = ((unsigned int)u) << 16; return v.f;
}
__device__ __forceinline__ unsigned short f2bf(float f) {
    union { float f; unsigned int i; } v; v.f = f;
    unsigned int r = v.i + 0x7fff + ((v.i >> 16) & 1);   // RNE (no NaN inputs here)
    return (unsigned short)(r >> 16);
}
__device__ __forceinline__ float4 u2f4(ushort4 u) {
    float4 f; f.x = bf2f(u.x); f.y = bf2f(u.y); f.z = bf2f(u.z); f.w = bf2f(u.w);
    return f;
}
__device__ __forceinline__ ushort4 f2u4(float4 f) {
    ushort4 u; u.x = f2bf(f.x); u.y = f2bf(f.y); u.z = f2bf(f.z); u.w = f2bf(f.w);
    return u;
}
__device__ __forceinline__ float4 fma4(float4 a, float s, float4 c) {
    c.x = fmaf(a.x, s, c.x); c.y = fmaf(a.y, s, c.y);
    c.z = fmaf(a.z, s, c.z); c.w = fmaf(a.w, s, c.w);
    return c;
}
__device__ __forceinline__ float4 add4(float4 a, float4 b) {
    float4 r; r.x = a.x + b.x; r.y = a.y + b.y; r.z = a.z + b.z; r.w = a.w + b.w;
    return r;
}

// ---- deg (LDS histograms, ZERO global atomics) + emb fp32->bf16 convert ----
// Block (g,r,c) histograms chunk c's dsts falling in node-range r into private
// LDS (on-CU atomics), then PLAIN-stores to hist[c] -- one writer per cell.
__global__ __launch_bounds__(1024) void deg_cvt_kernel(
        const int* __restrict__ up, const int* __restrict__ ut,
        const int* __restrict__ ug, int* __restrict__ hist,
        const float4* __restrict__ e0, const float4* __restrict__ e1,
        const float4* __restrict__ e2, ushort4* __restrict__ embh,
        int NP, int NT, int NG, int NTOT, int E) {
    __shared__ int lh[LDSH];
    int b = blockIdx.x;
    const int HB = 3 * RNG * CHK;
    if (b < HB) {
        int c  = b & (CHK - 1);
        int gr = b >> 4;             // CHK==16
        int g  = gr >> 3;            // RNG==8
        int r  = gr & (RNG - 1);
        const int* edge = (g == 0) ? up : (g == 1) ? ut : ug;
        int nb = (g == 0) ? 0 : (g == 1) ? NP : NP + NT;
        int Ng = (g == 0) ? NP : (g == 1) ? NT : NG;
        int Q  = (Ng + RNG - 1) / RNG;
        int lo = r * Q;
        int hi = lo + Q; if (hi > Ng) hi = Ng;
        int nloc = hi - lo;
        for (int t = threadIdx.x; t < nloc; t += 1024) lh[t] = 0;
        __syncthreads();
        int CE = (E + CHK - 1) / CHK;
        int jb = c * CE, je = jb + CE; if (je > E) je = E;
        for (int j = jb + threadIdx.x; j < je; j += 1024) {
            int t = edge[E + j];                         // dst (local id)
            if (t >= lo && t < hi) atomicAdd(&lh[t - lo], 1);
        }
        __syncthreads();
        for (int t = threadIdx.x; t < nloc; t += 1024)
            hist[(size_t)c * NTOT + nb + lo + t] = lh[t];
        return;
    }
    // ---- emb conversion blocks ----
    int i2 = (b - HB) * 1024 + threadIdx.x;
    int np16 = NP * 16, nt16 = NT * 16, ng16 = NG * 16;
    if (i2 >= np16 + nt16 + ng16) return;
    const float4* s; int j;
    if (i2 < np16)              { s = e0; j = i2; }
    else if (i2 < np16 + nt16)  { s = e1; j = i2 - np16; }
    else                        { s = e2; j = i2 - np16 - nt16; }
    embh[i2] = f2u4(s[j]);
}

// ---- chunk-prefix + total degree (removes permute's serial O(c) hist loop,
//      and lets scan kernels read deg once instead of CHK strided arrays) ----
__global__ void sumdeg_kernel(const int* __restrict__ hist, int* __restrict__ csum,
                              int* __restrict__ deg, int n) {
    int i = blockIdx.x * 256 + threadIdx.x;
    if (i >= n) return;
    int run = 0;
#pragma unroll
    for (int c = 0; c < CHK; ++c) {
        csum[(size_t)c * n + i] = run;          // exclusive chunk prefix
        run += hist[(size_t)c * n + i];
    }
    deg[i] = run;
}

// ---- parallel scan, stage 1: per-block (256-elem) sums over deg ----
__global__ void block_sums(const int* __restrict__ deg, int* __restrict__ bsum,
                           int n) {
    int i = blockIdx.x * 256 + threadIdx.x;
    int v = (i < n) ? deg[i] : 0;
#pragma unroll
    for (int s = 1; s < 64; s <<= 1) v += __shfl_xor(v, s, 64);
    __shared__ int ws[4];
    if ((threadIdx.x & 63) == 0) ws[threadIdx.x >> 6] = v;
    __syncthreads();
    if (threadIdx.x == 0) bsum[blockIdx.x] = ws[0] + ws[1] + ws[2] + ws[3];
}

// ---- stage 2: exclusive scan of block sums (single block, nb <= 1024) ----
__global__ void scan_bsums(int* __restrict__ bsum, int nb) {
    int lane = threadIdx.x & 63, wid = threadIdx.x >> 6;
    int v = (threadIdx.x < nb) ? bsum[threadIdx.x] : 0;
    int x = v;
#pragma unroll
    for (int s = 1; s < 64; s <<= 1) {
        int y = __shfl_up(x, s, 64);
        if (lane >= s) x += y;
    }
    __shared__ int ws[16];
    if (lane == 63) ws[wid] = x;
    __syncthreads();
    int pre = 0;
    for (int w2 = 0; w2 < wid; ++w2) pre += ws[w2];
    if (threadIdx.x < nb) bsum[threadIdx.x] = pre + x - v;   // exclusive
}

// ---- stage 3: global exclusive offsets + dinv ----
__global__ void scatter_offs(const int* __restrict__ deg, const int* __restrict__ bpre,
                             int* __restrict__ offs, float* __restrict__ dinv,
                             int n, int total) {
    int i = blockIdx.x * 256 + threadIdx.x;
    int lane = threadIdx.x & 63, wid = threadIdx.x >> 6;
    int v = (i < n) ? deg[i] : 0;
    int x = v;
#pragma unroll
    for (int s = 1; s < 64; s <<= 1) {
        int y = __shfl_up(x, s, 64);
        if (lane >= s) x += y;
    }
    __shared__ int ws[4];
    if (lane == 63) ws[wid] = x;
    __syncthreads();
    int pre = bpre[blockIdx.x];
    for (int w2 = 0; w2 < wid; ++w2) pre += ws[w2];
    if (i < n) {
        int e = pre + x - v;
        offs[i] = e;
        dinv[i] = (v > 0) ? rsqrtf((float)v) : 0.0f;
    }
    if (i == 0) offs[n] = total;
}

// ---- permute into dst-sorted CSR order (ZERO global atomics) ----
// Block (g,r,c): LDS cursors seeded from offs + precomputed csum (coalesced,
// no serial prefix loop). XCD-ALIGNED DECODE: b = c*24 + gr; 24%8==0 so
// b%8 == gr%8 -- all CHK chunks of one (g,r) land on the SAME XCD, so each
// 64B ei line is assembled in one L2 and written back once (round-9 fix).
__global__ __launch_bounds__(1024) void permute3_kernel(
        const int* __restrict__ up, const int* __restrict__ ut,
        const int* __restrict__ ug, const int* __restrict__ offs,
        const int* __restrict__ csum, int* __restrict__ ei,
        int NP, int NT, int NG, int NTOT, int E) {
    __shared__ int lcur[LDSH];
    int b = blockIdx.x;
    int c  = b / 24;                 // chunk (0..CHK-1); 24 = 3*RNG (g,r) pairs
    int gr = b - c * 24;             // (g,r); b%8 == gr%8 -> XCD-aligned
    int g  = gr >> 3;
    int r  = gr & (RNG - 1);
    const int* edge = (g == 0) ? up : (g == 1) ? ut : ug;
    int nb = (g == 0) ? 0 : (g == 1) ? NP : NP + NT;
    int Ng = (g == 0) ? NP : (g == 1) ? NT : NG;
    int Q  = (Ng + RNG - 1) / RNG;
    int lo = r * Q;
    int hi = lo + Q; if (hi > Ng) hi = Ng;
    int nloc = hi - lo;
    for (int t = threadIdx.x; t < nloc; t += 1024)
        lcur[t] = offs[nb + lo + t] + csum[(size_t)c * NTOT + nb + lo + t];
    __syncthreads();
    int CE = (E + CHK - 1) / CHK;
    int jb = c * CE, je = jb + CE; if (je > E) je = E;
    for (int j = jb + threadIdx.x; j < je; j += 1024) {
        int t = edge[E + j];                             // dst (local id)
        if (t >= lo && t < hi) {
            int p = atomicAdd(&lcur[t - lo], 1);         // LDS atomic (on-CU)
            ei[p] = edge[j] + nb;                        // global src id
        }
    }
}

// ---- conv layer 1: x1[n] = dinv[n] * sum_in emb[s]*dinv[s]  (bf16 rows) ----
// 4 independent accumulators break the per-component FMA dep chain.
__global__ void conv_csr1(const int* __restrict__ offs, const int* __restrict__ ei,
                          const float* __restrict__ dinv,
                          const ushort4* __restrict__ xin, ushort4* __restrict__ xout, int N) {
    int gid = blockIdx.x * blockDim.x + threadIdx.x;
    int n = gid >> 4, l = gid & 15;
    if (n >= N) return;
    int beg = offs[n], end = offs[n + 1];
    float4 a0 = {0.f, 0.f, 0.f, 0.f}, a1 = a0, a2 = a0, a3 = a0;
    int k = beg;
    for (; k + 3 < end; k += 4) {
        int s0 = ei[k], s1 = ei[k + 1], s2 = ei[k + 2], s3 = ei[k + 3];
        float w0 = dinv[s0], w1 = dinv[s1], w2 = dinv[s2], w3 = dinv[s3];
        ushort4 u0 = xin[(size_t)s0 * 16 + l];
        ushort4 u1 = xin[(size_t)s1 * 16 + l];
        ushort4 u2 = xin[(size_t)s2 * 16 + l];
        ushort4 u3 = xin[(size_t)s3 * 16 + l];
        a0 = fma4(u2f4(u0), w0, a0);
        a1 = fma4(u2f4(u1), w1, a1);
        a2 = fma4(u2f4(u2), w2, a2);
        a3 = fma4(u2f4(u3), w3, a3);
    }
    for (; k < end; ++k) {
        int s = ei[k];
        a0 = fma4(u2f4(xin[(size_t)s * 16 + l]), dinv[s], a0);
    }
    float4 acc = add4(add4(a0, a1), add4(a2, a3));
    float sc = dinv[n];
    float4 r; r.x = acc.x * sc; r.y = acc.y * sc; r.z = acc.z * sc; r.w = acc.w * sc;
    xout[(size_t)n * 16 + l] = f2u4(r);
}

// ---- conv layer 2 + epilogue: out[n] = (emb + x1 + dinv[n]*sum x1[s]*dinv[s]) / 3 ----
__global__ void conv_csr2(const int* __restrict__ offs, const int* __restrict__ ei,
                          const float* __restrict__ dinv,
                          const ushort4* __restrict__ emb, const ushort4* __restrict__ x1,
                          ushort4* __restrict__ out, int N) {
    int gid = blockIdx.x * blockDim.x + threadIdx.x;
    int n = gid >> 4, l = gid & 15;
    if (n >= N) return;
    int beg = offs[n], end = offs[n + 1];
    float4 a0 = {0.f, 0.f, 0.f, 0.f}, a1 = a0, a2 = a0, a3 = a0;
    int k = beg;
    for (; k + 3 < end; k += 4) {
        int s0 = ei[k], s1 = ei[k + 1], s2 = ei[k + 2], s3 = ei[k + 3];
        float w0 = dinv[s0], w1 = dinv[s1], w2 = dinv[s2], w3 = dinv[s3];
        ushort4 u0 = x1[(size_t)s0 * 16 + l];
        ushort4 u1 = x1[(size_t)s1 * 16 + l];
        ushort4 u2 = x1[(size_t)s2 * 16 + l];
        ushort4 u3 = x1[(size_t)s3 * 16 + l];
        a0 = fma4(u2f4(u0), w0, a0);
        a1 = fma4(u2f4(u1), w1, a1);
        a2 = fma4(u2f4(u2), w2, a2);
        a3 = fma4(u2f4(u3), w3, a3);
    }
    for (; k < end; ++k) {
        int s = ei[k];
        a0 = fma4(u2f4(x1[(size_t)s * 16 + l]), dinv[s], a0);
    }
    float4 acc = add4(add4(a0, a1), add4(a2, a3));
    float sc = dinv[n];
    size_t idx = (size_t)n * 16 + l;
    float4 em = u2f4(emb[idx]), x = u2f4(x1[idx]);
    const float third = 1.0f / 3.0f;
    float4 o;
    o.x = (em.x + x.x + acc.x * sc) * third;
    o.y = (em.y + x.y + acc.y * sc) * third;
    o.z = (em.z + x.z + acc.z * sc) * third;
    o.w = (em.w + x.w + acc.w * sc) * third;
    out[idx] = f2u4(o);
}

// ---- final (round-1 proven version: VGPR 48, occ ~48%, ~75us) ----
// 4 edges per 16-lane group; weights in LDS; loads phase-ordered. Failed
// replacements (ledger): wave-per-edge 250us, reg-features 119us,
// LDS-features 100us -- occupancy dominates LDS-op count for this kernel.
__global__ void final_kernel(const int* __restrict__ up_e, const int* __restrict__ ut_e,
                             const int* __restrict__ utag_e,
                             const float* __restrict__ src_feat, const float* __restrict__ dst_feat,
                             const ushort4* __restrict__ O,
                             const float4* __restrict__ W_s4, const float4* __restrict__ b_s4,
                             const float4* __restrict__ W_d4, const float4* __restrict__ b_d4,
                             float* __restrict__ out, int E, int NP, int NT) {
    __shared__ float4 LWs[256], LWd[256];
    int tid = threadIdx.x;
    LWs[tid] = W_s4[tid];          // 16x16 float4 = full [16,64] weight matrix
    LWd[tid] = W_d4[tid];
    __syncthreads();

    int gid = blockIdx.x * blockDim.x + tid;
    int grp = gid >> 4;
    int l = gid & 15;
    int e0 = grp * 4;
    if (e0 >= E) return;
    int lane = tid & 63;
    int gbase = lane & 48;

    // ---- phase 0: edge indices + features + biases (issued FIRST) ----
    int sp[4], dp[4], st[4], dt[4], sg[4], dg[4];
    float fsc[4], fdc[4];
#pragma unroll
    for (int j = 0; j < 4; ++j) {
        int e = e0 + j; if (e > E - 1) e = E - 1;
        sp[j] = up_e[e];              dp[j] = up_e[E + e];
        st[j] = ut_e[e] + NP;         dt[j] = ut_e[E + e] + NP;
        sg[j] = utag_e[e] + NP + NT;  dg[j] = utag_e[E + e] + NP + NT;
        fsc[j] = src_feat[(size_t)e * 16 + l];
        fdc[j] = dst_feat[(size_t)e * 16 + l];
    }
    float4 bsv = b_s4[l], bdv = b_d4[l];

    // ---- phase 1: the 24 random O-row gathers ----
    ushort4 as[4][3], bs[4][3];
#pragma unroll
    for (int j = 0; j < 4; ++j) {
        as[j][0] = O[(size_t)sp[j] * 16 + l];
        as[j][1] = O[(size_t)st[j] * 16 + l];
        as[j][2] = O[(size_t)sg[j] * 16 + l];
        bs[j][0] = O[(size_t)dp[j] * 16 + l];
        bs[j][1] = O[(size_t)dt[j] * 16 + l];
        bs[j][2] = O[(size_t)dg[j] * 16 + l];
    }

    // ---- phase 2: f32 feature GEMM from LDS weights (overlaps gathers) ----
    float4 fs[4], fd[4];
#pragma unroll
    for (int j = 0; j < 4; ++j) { fs[j] = bsv; fd[j] = bdv; }

#pragma unroll
    for (int k = 0; k < 16; ++k) {
        float4 ws = LWs[k * 16 + l];
        float4 wd = LWd[k * 16 + l];
#pragma unroll
        for (int j = 0; j < 4; ++j) {
            float a = __shfl(fsc[j], gbase + k, 64);
            float c = __shfl(fdc[j], gbase + k, 64);
            fs[j] = fma4(ws, a, fs[j]);
            fd[j] = fma4(wd, c, fd[j]);
        }
    }

    // ---- phase 3: epilogue (waits on gathers) ----
    const float third = 1.0f / 3.0f;
    float prod[4];
#pragma unroll
    for (int j = 0; j < 4; ++j) {
        float4 vp = u2f4(as[j][0]), vt = u2f4(as[j][1]), vg = u2f4(as[j][2]);
        float4 P, Q;
        P.x = (vp.x + vt.x + vg.x) * third + fs[j].x;
        P.y = (vp.y + vt.y + vg.y) * third + fs[j].y;
        P.z = (vp.z + vt.z + vg.z) * third + fs[j].z;
        P.w = (vp.w + vt.w + vg.w) * third + fs[j].w;
        vp = u2f4(bs[j][0]); vt = u2f4(bs[j][1]); vg = u2f4(bs[j][2]);
        Q.x = (vp.x + vt.x + vg.x) * third + fd[j].x;
        Q.y = (vp.y + vt.y + vg.y) * third + fd[j].y;
        Q.z = (vp.z + vt.z + vg.z) * third + fd[j].z;
        Q.w = (vp.w + vt.w + vg.w) * third + fd[j].w;
        float p = P.x * Q.x + P.y * Q.y + P.z * Q.z + P.w * Q.w;
        p += __shfl_xor(p, 8, 64);
        p += __shfl_xor(p, 4, 64);
        p += __shfl_xor(p, 2, 64);
        p += __shfl_xor(p, 1, 64);
        prod[j] = p;
    }
    if (l == 0) {
#pragma unroll
        for (int j = 0; j < 4; ++j)
            if (e0 + j < E) out[e0 + j] = prod[j];
    }
}

extern "C" void kernel_launch(void* const* d_in, const int* in_sizes, int n_in,
                              void* d_out, int out_size, void* d_ws, size_t ws_size,
                              hipStream_t stream) {
    const int*   up_e     = (const int*)d_in[0];
    const int*   ut_e     = (const int*)d_in[1];
    const int*   utag_e   = (const int*)d_in[2];
    const float* src_feat = (const float*)d_in[3];
    const float* dst_feat = (const float*)d_in[4];
    const float* up_emb   = (const float*)d_in[5];
    const float* ut_emb   = (const float*)d_in[6];
    const float* utag_emb = (const float*)d_in[7];
    const float* W_src    = (const float*)d_in[8];
    const float* b_src    = (const float*)d_in[9];
    const float* W_dst    = (const float*)d_in[10];
    const float* b_dst    = (const float*)d_in[11];
    float* out = (float*)d_out;

    const int E  = in_sizes[0] / 2;
    const int NP = in_sizes[5] / DIM;
    const int NT = in_sizes[6] / DIM;
    const int NG = in_sizes[7] / DIM;
    const int NTOT = NP + NT + NG;
    const int NB = (NTOT + 255) / 256;          // scan blocks

    // ---- workspace layout ----
    char* w = (char*)d_ws;
    int*  hist = (int*)w;                       w += (size_t)CHK * NTOT * 4;  // chunk hists
    int*  csum = (int*)w;                       w += (size_t)CHK * NTOT * 4;  // chunk prefixes
    int*  deg  = (int*)w;                       w += (size_t)NTOT * 4;
    int*  offs = (int*)w;                       w += (size_t)(NTOT + 1) * 4;
    int*  bsum = (int*)w;                       w += (size_t)1024 * 4;
    float* dinv = (float*)w;                    w += (size_t)NTOT * 4;
    w = (char*)(((uintptr_t)w + 127) & ~(uintptr_t)127);
    int*  ei   = (int*)w;                       w += (size_t)3 * E * 4;
    w = (char*)(((uintptr_t)w + 127) & ~(uintptr_t)127);
    ushort4* embh = (ushort4*)w;                w += (size_t)NTOT * 16 * 8;   // bf16 emb
    ushort4* x1h  = (ushort4*)w;                w += (size_t)NTOT * 16 * 8;   // bf16 x1
    ushort4* outh = (ushort4*)w;                // bf16 aggregated node table

    const int BT = 256;
    const int HB = 3 * RNG * CHK;               // histogram blocks (384)

    // deg histograms (atomic-free) + emb bf16 convert, fused
    {
        int convBlocks = (NTOT * 16 + 1023) / 1024;
        deg_cvt_kernel<<<dim3(HB + convBlocks), dim3(1024), 0, stream>>>(
            up_e, ut_e, utag_e, hist,
            (const float4*)up_emb, (const float4*)ut_emb, (const float4*)utag_emb,
            embh, NP, NT, NG, NTOT, E);
    }

    // chunk prefixes + total degree
    sumdeg_kernel<<<dim3(NB), dim3(BT), 0, stream>>>(hist, csum, deg, NTOT);

    // global parallel exclusive scan over deg (+ dinv)
    block_sums<<<dim3(NB), dim3(BT), 0, stream>>>(deg, bsum, NTOT);
    scan_bsums<<<dim3(1), dim3(1024), 0, stream>>>(bsum, NB);
    scatter_offs<<<dim3(NB), dim3(BT), 0, stream>>>(deg, bsum, offs, dinv, NTOT, 3 * E);

    // CSR build: LDS cursors from offs+csum, XCD-aligned chunk blocks
    permute3_kernel<<<dim3(CHK * 24), dim3(1024), 0, stream>>>(
        up_e, ut_e, utag_e, offs, csum, ei, NP, NT, NG, NTOT, E);

    // conv layers over ALL nodes
    int nb = ((size_t)NTOT * 16 + BT - 1) / BT;
    conv_csr1<<<dim3(nb), dim3(BT), 0, stream>>>(offs, ei, dinv, embh, x1h, NTOT);
    conv_csr2<<<dim3(nb), dim3(BT), 0, stream>>>(offs, ei, dinv, embh, x1h, outh, NTOT);

    // final: 4 edges per 16-lane group (round-1 configuration)
    long long groups = (E + 3) / 4;
    final_kernel<<<dim3((groups * 16 + BT - 1) / BT), dim3(BT), 0, stream>>>(
        up_e, ut_e, utag_e, src_feat, dst_feat, outh,
        (const float4*)W_src, (const float4*)b_src,
        (const float4*)W_dst, (const float4*)b_dst, out, E, NP, NT);
}

// Round 12
// 329.082 us; speedup vs baseline: 2.8372x; 1.0107x over previous
//
#include <hip/hip_runtime.h>

#define DIM 64
#define RNG 8        // node ranges per graph (LDS-owned)
#define CHK 16       // edge chunks per graph (384 blocks ~1.5/CU)
#define LDSH 14336   // LDS histogram/cursor capacity (ints); ceil(110000/8)=13750 fits

typedef __attribute__((ext_vector_type(4))) short s16x4;
typedef __attribute__((ext_vector_type(4))) float f32x4v;

__device__ __forceinline__ float bf2f(unsigned short u) {
    union { unsigned int i; float f; } v; v.i = ((unsigned int)u) << 16; return v.f;
}
__device__ __forceinline__ unsigned short f2bf(float f) {
    union { float f; unsigned int i; } v; v.f = f;
    unsigned int r = v.i + 0x7fff + ((v.i >> 16) & 1);   // RNE (no NaN inputs here)
    return (unsigned short)(r >> 16);
}
__device__ __forceinline__ float4 u2f4(ushort4 u) {
    float4 f; f.x = bf2f(u.x); f.y = bf2f(u.y); f.z = bf2f(u.z); f.w = bf2f(u.w);
    return f;
}
__device__ __forceinline__ ushort4 f2u4(float4 f) {
    ushort4 u; u.x = f2bf(f.x); u.y = f2bf(f.y); u.z = f2bf(f.z); u.w = f2bf(f.w);
    return u;
}
__device__ __forceinline__ float4 fma4(float4 a, float s, float4 c) {
    c.x = fmaf(a.x, s, c.x); c.y = fmaf(a.y, s, c.y);
    c.z = fmaf(a.z, s, c.z); c.w = fmaf(a.w, s, c.w);
    return c;
}
__device__ __forceinline__ float4 add4(float4 a, float4 b) {
    float4 r; r.x = a.x + b.x; r.y = a.y + b.y; r.z = a.z + b.z; r.w = a.w + b.w;
    return r;
}

// ---- deg (LDS histograms, ZERO global atomics) + emb fp32->bf16 convert
//      + one ride-along block building the bf16 MFMA B-fragment table ----
// wfrag layout: [m (0=src,1=dst)][tile t 0..3][lane 0..63] -> s16x4 where
// frag elem j = bf16( W_m[(4*(l>>4)+j)*64 + 4*(l&15) + t] )  (B-operand layout
// of mfma 16x16x16: lane l holds B[k=4*(l>>4)+j][col=l&15]; tile t covers
// output dims {4c+t} -- a column permutation matching the ushort4 gathers).
__global__ __launch_bounds__(1024) void deg_cvt_kernel(
        const int* __restrict__ up, const int* __restrict__ ut,
        const int* __restrict__ ug, int* __restrict__ hist,
        const float4* __restrict__ e0, const float4* __restrict__ e1,
        const float4* __restrict__ e2, ushort4* __restrict__ embh,
        const float* __restrict__ W_s, const float* __restrict__ W_d,
        s16x4* __restrict__ wfrag,
        int NP, int NT, int NG, int NTOT, int E) {
    __shared__ int lh[LDSH];
    int b = blockIdx.x;
    const int HB = 3 * RNG * CHK;
    if (b < HB) {
        int c  = b & (CHK - 1);
        int gr = b >> 4;             // CHK==16
        int g  = gr >> 3;            // RNG==8
        int r  = gr & (RNG - 1);
        const int* edge = (g == 0) ? up : (g == 1) ? ut : ug;
        int nb = (g == 0) ? 0 : (g == 1) ? NP : NP + NT;
        int Ng = (g == 0) ? NP : (g == 1) ? NT : NG;
        int Q  = (Ng + RNG - 1) / RNG;
        int lo = r * Q;
        int hi = lo + Q; if (hi > Ng) hi = Ng;
        int nloc = hi - lo;
        for (int t = threadIdx.x; t < nloc; t += 1024) lh[t] = 0;
        __syncthreads();
        int CE = (E + CHK - 1) / CHK;
        int jb = c * CE, je = jb + CE; if (je > E) je = E;
        for (int j = jb + threadIdx.x; j < je; j += 1024) {
            int t = edge[E + j];                         // dst (local id)
            if (t >= lo && t < hi) atomicAdd(&lh[t - lo], 1);
        }
        __syncthreads();
        for (int t = threadIdx.x; t < nloc; t += 1024)
            hist[(size_t)c * NTOT + nb + lo + t] = lh[t];
        return;
    }
    int convBlocks = (NTOT * 16 + 1023) / 1024;
    if (b >= HB + convBlocks) {
        // ---- build wfrag (512 entries of s16x4) ----
        int i = threadIdx.x;
        if (i < 512) {
            int m = i >> 8;              // matrix (0=src,1=dst)
            int t = (i >> 6) & 3;        // tile
            int l = i & 63;              // lane
            int q = l >> 4, cc = l & 15;
            const float* Wm = m ? W_d : W_s;
            s16x4 v;
#pragma unroll
            for (int j = 0; j < 4; ++j)
                v[j] = (short)f2bf(Wm[(4 * q + j) * 64 + 4 * cc + t]);
            wfrag[i] = v;
        }
        return;
    }
    // ---- emb conversion blocks ----
    int i2 = (b - HB) * 1024 + threadIdx.x;
    int np16 = NP * 16, nt16 = NT * 16, ng16 = NG * 16;
    if (i2 >= np16 + nt16 + ng16) return;
    const float4* s; int j;
    if (i2 < np16)              { s = e0; j = i2; }
    else if (i2 < np16 + nt16)  { s = e1; j = i2 - np16; }
    else                        { s = e2; j = i2 - np16 - nt16; }
    embh[i2] = f2u4(s[j]);
}

// ---- chunk-prefix + total degree ----
__global__ void sumdeg_kernel(const int* __restrict__ hist, int* __restrict__ csum,
                              int* __restrict__ deg, int n) {
    int i = blockIdx.x * 256 + threadIdx.x;
    if (i >= n) return;
    int run = 0;
#pragma unroll
    for (int c = 0; c < CHK; ++c) {
        csum[(size_t)c * n + i] = run;          // exclusive chunk prefix
        run += hist[(size_t)c * n + i];
    }
    deg[i] = run;
}

// ---- parallel scan, stage 1: per-block (256-elem) sums over deg ----
__global__ void block_sums(const int* __restrict__ deg, int* __restrict__ bsum,
                           int n) {
    int i = blockIdx.x * 256 + threadIdx.x;
    int v = (i < n) ? deg[i] : 0;
#pragma unroll
    for (int s = 1; s < 64; s <<= 1) v += __shfl_xor(v, s, 64);
    __shared__ int ws[4];
    if ((threadIdx.x & 63) == 0) ws[threadIdx.x >> 6] = v;
    __syncthreads();
    if (threadIdx.x == 0) bsum[blockIdx.x] = ws[0] + ws[1] + ws[2] + ws[3];
}

// ---- stage 2: exclusive scan of block sums (single block, nb <= 1024) ----
__global__ void scan_bsums(int* __restrict__ bsum, int nb) {
    int lane = threadIdx.x & 63, wid = threadIdx.x >> 6;
    int v = (threadIdx.x < nb) ? bsum[threadIdx.x] : 0;
    int x = v;
#pragma unroll
    for (int s = 1; s < 64; s <<= 1) {
        int y = __shfl_up(x, s, 64);
        if (lane >= s) x += y;
    }
    __shared__ int ws[16];
    if (lane == 63) ws[wid] = x;
    __syncthreads();
    int pre = 0;
    for (int w2 = 0; w2 < wid; ++w2) pre += ws[w2];
    if (threadIdx.x < nb) bsum[threadIdx.x] = pre + x - v;   // exclusive
}

// ---- stage 3: global exclusive offsets + dinv ----
__global__ void scatter_offs(const int* __restrict__ deg, const int* __restrict__ bpre,
                             int* __restrict__ offs, float* __restrict__ dinv,
                             int n, int total) {
    int i = blockIdx.x * 256 + threadIdx.x;
    int lane = threadIdx.x & 63, wid = threadIdx.x >> 6;
    int v = (i < n) ? deg[i] : 0;
    int x = v;
#pragma unroll
    for (int s = 1; s < 64; s <<= 1) {
        int y = __shfl_up(x, s, 64);
        if (lane >= s) x += y;
    }
    __shared__ int ws[4];
    if (lane == 63) ws[wid] = x;
    __syncthreads();
    int pre = bpre[blockIdx.x];
    for (int w2 = 0; w2 < wid; ++w2) pre += ws[w2];
    if (i < n) {
        int e = pre + x - v;
        offs[i] = e;
        dinv[i] = (v > 0) ? rsqrtf((float)v) : 0.0f;
    }
    if (i == 0) offs[n] = total;
}

// ---- permute into dst-sorted CSR order (ZERO global atomics) ----
// XCD-ALIGNED DECODE: b = c*24 + gr; 24%8==0 so b%8 == gr%8 -- all CHK chunks
// of one (g,r) land on the SAME XCD; each 64B ei line written back once, full.
__global__ __launch_bounds__(1024) void permute3_kernel(
        const int* __restrict__ up, const int* __restrict__ ut,
        const int* __restrict__ ug, const int* __restrict__ offs,
        const int* __restrict__ csum, int* __restrict__ ei,
        int NP, int NT, int NG, int NTOT, int E) {
    __shared__ int lcur[LDSH];
    int b = blockIdx.x;
    int c  = b / 24;                 // chunk (0..CHK-1); 24 = 3*RNG (g,r) pairs
    int gr = b - c * 24;             // (g,r); b%8 == gr%8 -> XCD-aligned
    int g  = gr >> 3;
    int r  = gr & (RNG - 1);
    const int* edge = (g == 0) ? up : (g == 1) ? ut : ug;
    int nb = (g == 0) ? 0 : (g == 1) ? NP : NP + NT;
    int Ng = (g == 0) ? NP : (g == 1) ? NT : NG;
    int Q  = (Ng + RNG - 1) / RNG;
    int lo = r * Q;
    int hi = lo + Q; if (hi > Ng) hi = Ng;
    int nloc = hi - lo;
    for (int t = threadIdx.x; t < nloc; t += 1024)
        lcur[t] = offs[nb + lo + t] + csum[(size_t)c * NTOT + nb + lo + t];
    __syncthreads();
    int CE = (E + CHK - 1) / CHK;
    int jb = c * CE, je = jb + CE; if (je > E) je = E;
    for (int j = jb + threadIdx.x; j < je; j += 1024) {
        int t = edge[E + j];                             // dst (local id)
        if (t >= lo && t < hi) {
            int p = atomicAdd(&lcur[t - lo], 1);         // LDS atomic (on-CU)
            ei[p] = edge[j] + nb;                        // global src id
        }
    }
}

// ---- conv layer 1: x1[n] = dinv[n] * sum_in emb[s]*dinv[s]  (bf16 rows) ----
__global__ void conv_csr1(const int* __restrict__ offs, const int* __restrict__ ei,
                          const float* __restrict__ dinv,
                          const ushort4* __restrict__ xin, ushort4* __restrict__ xout, int N) {
    int gid = blockIdx.x * blockDim.x + threadIdx.x;
    int n = gid >> 4, l = gid & 15;
    if (n >= N) return;
    int beg = offs[n], end = offs[n + 1];
    float4 a0 = {0.f, 0.f, 0.f, 0.f}, a1 = a0, a2 = a0, a3 = a0;
    int k = beg;
    for (; k + 3 < end; k += 4) {
        int s0 = ei[k], s1 = ei[k + 1], s2 = ei[k + 2], s3 = ei[k + 3];
        float w0 = dinv[s0], w1 = dinv[s1], w2 = dinv[s2], w3 = dinv[s3];
        ushort4 u0 = xin[(size_t)s0 * 16 + l];
        ushort4 u1 = xin[(size_t)s1 * 16 + l];
        ushort4 u2 = xin[(size_t)s2 * 16 + l];
        ushort4 u3 = xin[(size_t)s3 * 16 + l];
        a0 = fma4(u2f4(u0), w0, a0);
        a1 = fma4(u2f4(u1), w1, a1);
        a2 = fma4(u2f4(u2), w2, a2);
        a3 = fma4(u2f4(u3), w3, a3);
    }
    for (; k < end; ++k) {
        int s = ei[k];
        a0 = fma4(u2f4(xin[(size_t)s * 16 + l]), dinv[s], a0);
    }
    float4 acc = add4(add4(a0, a1), add4(a2, a3));
    float sc = dinv[n];
    float4 r; r.x = acc.x * sc; r.y = acc.y * sc; r.z = acc.z * sc; r.w = acc.w * sc;
    xout[(size_t)n * 16 + l] = f2u4(r);
}

// ---- conv layer 2 + epilogue ----
__global__ void conv_csr2(const int* __restrict__ offs, const int* __restrict__ ei,
                          const float* __restrict__ dinv,
                          const ushort4* __restrict__ emb, const ushort4* __restrict__ x1,
                          ushort4* __restrict__ out, int N) {
    int gid = blockIdx.x * blockDim.x + threadIdx.x;
    int n = gid >> 4, l = gid & 15;
    if (n >= N) return;
    int beg = offs[n], end = offs[n + 1];
    float4 a0 = {0.f, 0.f, 0.f, 0.f}, a1 = a0, a2 = a0, a3 = a0;
    int k = beg;
    for (; k + 3 < end; k += 4) {
        int s0 = ei[k], s1 = ei[k + 1], s2 = ei[k + 2], s3 = ei[k + 3];
        float w0 = dinv[s0], w1 = dinv[s1], w2 = dinv[s2], w3 = dinv[s3];
        ushort4 u0 = x1[(size_t)s0 * 16 + l];
        ushort4 u1 = x1[(size_t)s1 * 16 + l];
        ushort4 u2 = x1[(size_t)s2 * 16 + l];
        ushort4 u3 = x1[(size_t)s3 * 16 + l];
        a0 = fma4(u2f4(u0), w0, a0);
        a1 = fma4(u2f4(u1), w1, a1);
        a2 = fma4(u2f4(u2), w2, a2);
        a3 = fma4(u2f4(u3), w3, a3);
    }
    for (; k < end; ++k) {
        int s = ei[k];
        a0 = fma4(u2f4(x1[(size_t)s * 16 + l]), dinv[s], a0);
    }
    float4 acc = add4(add4(a0, a1), add4(a2, a3));
    float sc = dinv[n];
    size_t idx = (size_t)n * 16 + l;
    float4 em = u2f4(emb[idx]), x = u2f4(x1[idx]);
    const float third = 1.0f / 3.0f;
    float4 o;
    o.x = (em.x + x.x + acc.x * sc) * third;
    o.y = (em.y + x.y + acc.y * sc) * third;
    o.z = (em.z + x.z + acc.z * sc) * third;
    o.w = (em.w + x.w + acc.w * sc) * third;
    out[idx] = f2u4(o);
}

// ---- final v7: MFMA feature GEMM ----
// Wave = 16 edges. Feature GEMM [16,16]@[16,64] = 8x mfma_f32_16x16x16bf16_1k
// (4 output tiles x {src,dst}), replacing ~1200cy of shfl-GEMM per wave.
// Tile t covers output dims {4c+t} (column-permuted W) so the MFMA C/D layout
// (col=lane&15, row=(lane>>4)*4+reg -- HW-verified) matches the r1 ushort4
// gather/epilogue layout EXACTLY; phases 0/1/3 are unchanged from r1.
// Load order: A-features + B-frags + biases FIRST, then indices+gathers --
// in-order vmcnt means the MFMAs wait only on A/B, overlapping the gathers.
__global__ __launch_bounds__(256) void final_kernel(
        const int* __restrict__ up_e, const int* __restrict__ ut_e,
        const int* __restrict__ utag_e,
        const float* __restrict__ src_feat, const float* __restrict__ dst_feat,
        const ushort4* __restrict__ O, const s16x4* __restrict__ wfrag,
        const float4* __restrict__ b_s4, const float4* __restrict__ b_d4,
        float* __restrict__ out, int E, int NP, int NT) {
    int tid = threadIdx.x;
    int wv = tid >> 6;             // wave in block
    int l  = tid & 63;             // lane
    int c  = l & 15;               // col = dim quad (dims 4c..4c+3)
    int q  = l >> 4;               // quad (0..3)
    int e0w = (blockIdx.x * 4 + wv) * 16;
    if (e0w >= E) return;

    // ---- phase 0a: A fragments (features of the wave's 16 edges, bf16) ----
    // A layout (16x16x16): lane l holds A[row=l&15][k=4*(l>>4)+j], j=0..3.
    int ea = e0w + c; if (ea > E - 1) ea = E - 1;
    float4 fa = *(const float4*)(src_feat + (size_t)ea * 16 + q * 4);
    float4 ga = *(const float4*)(dst_feat + (size_t)ea * 16 + q * 4);

    // ---- phase 0b: B fragments (precomputed bf16 table) + biases ----
    s16x4 Bs[4], Bd[4];
#pragma unroll
    for (int t = 0; t < 4; ++t) {
        Bs[t] = wfrag[t * 64 + l];
        Bd[t] = wfrag[256 + t * 64 + l];
    }
    float4 bsv = b_s4[c], bdv = b_d4[c];

    s16x4 As, Ad;
    As[0] = (short)f2bf(fa.x); As[1] = (short)f2bf(fa.y);
    As[2] = (short)f2bf(fa.z); As[3] = (short)f2bf(fa.w);
    Ad[0] = (short)f2bf(ga.x); Ad[1] = (short)f2bf(ga.y);
    Ad[2] = (short)f2bf(ga.z); Ad[3] = (short)f2bf(ga.w);

    // ---- phase 1: edge indices + 24 O-row gathers (lane c -> dims 4c..4c+3;
    //      quad q owns edges e0w + q*4 + r) ----
    ushort4 as[4][3], bs[4][3];
#pragma unroll
    for (int r = 0; r < 4; ++r) {
        int e = e0w + q * 4 + r; if (e > E - 1) e = E - 1;
        int sp = up_e[e],             dp = up_e[E + e];
        int st = ut_e[e] + NP,        dt = ut_e[E + e] + NP;
        int sg = utag_e[e] + NP + NT, dg = utag_e[E + e] + NP + NT;
        as[r][0] = O[(size_t)sp * 16 + c];
        as[r][1] = O[(size_t)st * 16 + c];
        as[r][2] = O[(size_t)sg * 16 + c];
        bs[r][0] = O[(size_t)dp * 16 + c];
        bs[r][1] = O[(size_t)dt * 16 + c];
        bs[r][2] = O[(size_t)dg * 16 + c];
    }
    __builtin_amdgcn_sched_barrier(0);   // pin gathers above the MFMAs

    // ---- phase 2: 8 MFMAs (wait only on A/B loads; gathers stay in flight) ----
    f32x4v Cs[4], Cd[4];
    f32x4v zz = {0.f, 0.f, 0.f, 0.f};
#pragma unroll
    for (int t = 0; t < 4; ++t) {
        Cs[t] = __builtin_amdgcn_mfma_f32_16x16x16bf16_1k(As, Bs[t], zz, 0, 0, 0);
        Cd[t] = __builtin_amdgcn_mfma_f32_16x16x16bf16_1k(Ad, Bd[t], zz, 0, 0, 0);
    }

    // ---- phase 3: epilogue (waits on gathers); C/D: row=(q*4+r), col=c ----
    const float third = 1.0f / 3.0f;
#pragma unroll
    for (int r = 0; r < 4; ++r) {
        int er = e0w + q * 4 + r;
        float4 fsv, fdv;
        fsv.x = Cs[0][r] + bsv.x; fsv.y = Cs[1][r] + bsv.y;
        fsv.z = Cs[2][r] + bsv.z; fsv.w = Cs[3][r] + bsv.w;
        fdv.x = Cd[0][r] + bdv.x; fdv.y = Cd[1][r] + bdv.y;
        fdv.z = Cd[2][r] + bdv.z; fdv.w = Cd[3][r] + bdv.w;
        float4 vp = u2f4(as[r][0]), vt = u2f4(as[r][1]), vg = u2f4(as[r][2]);
        float4 P, Q;
        P.x = (vp.x + vt.x + vg.x) * third + fsv.x;
        P.y = (vp.y + vt.y + vg.y) * third + fsv.y;
        P.z = (vp.z + vt.z + vg.z) * third + fsv.z;
        P.w = (vp.w + vt.w + vg.w) * third + fsv.w;
        vp = u2f4(bs[r][0]); vt = u2f4(bs[r][1]); vg = u2f4(bs[r][2]);
        Q.x = (vp.x + vt.x + vg.x) * third + fdv.x;
        Q.y = (vp.y + vt.y + vg.y) * third + fdv.y;
        Q.z = (vp.z + vt.z + vg.z) * third + fdv.z;
        Q.w = (vp.w + vt.w + vg.w) * third + fdv.w;
        float p = P.x * Q.x + P.y * Q.y + P.z * Q.z + P.w * Q.w;
        p += __shfl_xor(p, 8, 64);
        p += __shfl_xor(p, 4, 64);
        p += __shfl_xor(p, 2, 64);
        p += __shfl_xor(p, 1, 64);
        if (c == 0 && er < E) out[er] = p;
    }
}

extern "C" void kernel_launch(void* const* d_in, const int* in_sizes, int n_in,
                              void* d_out, int out_size, void* d_ws, size_t ws_size,
                              hipStream_t stream) {
    const int*   up_e     = (const int*)d_in[0];
    const int*   ut_e     = (const int*)d_in[1];
    const int*   utag_e   = (const int*)d_in[2];
    const float* src_feat = (const float*)d_in[3];
    const float* dst_feat = (const float*)d_in[4];
    const float* up_emb   = (const float*)d_in[5];
    const float* ut_emb   = (const float*)d_in[6];
    const float* utag_emb = (const float*)d_in[7];
    const float* W_src    = (const float*)d_in[8];
    const float* b_src    = (const float*)d_in[9];
    const float* W_dst    = (const float*)d_in[10];
    const float* b_dst    = (const float*)d_in[11];
    float* out = (float*)d_out;

    const int E  = in_sizes[0] / 2;
    const int NP = in_sizes[5] / DIM;
    const int NT = in_sizes[6] / DIM;
    const int NG = in_sizes[7] / DIM;
    const int NTOT = NP + NT + NG;
    const int NB = (NTOT + 255) / 256;          // scan blocks

    // ---- workspace layout ----
    char* w = (char*)d_ws;
    int*  hist = (int*)w;                       w += (size_t)CHK * NTOT * 4;  // chunk hists
    int*  csum = (int*)w;                       w += (size_t)CHK * NTOT * 4;  // chunk prefixes
    int*  deg  = (int*)w;                       w += (size_t)NTOT * 4;
    int*  offs = (int*)w;                       w += (size_t)(NTOT + 1) * 4;
    int*  bsum = (int*)w;                       w += (size_t)1024 * 4;
    float* dinv = (float*)w;                    w += (size_t)NTOT * 4;
    w = (char*)(((uintptr_t)w + 127) & ~(uintptr_t)127);
    s16x4* wfrag = (s16x4*)w;                   w += (size_t)512 * 8;         // bf16 W frags
    w = (char*)(((uintptr_t)w + 127) & ~(uintptr_t)127);
    int*  ei   = (int*)w;                       w += (size_t)3 * E * 4;
    w = (char*)(((uintptr_t)w + 127) & ~(uintptr_t)127);
    ushort4* embh = (ushort4*)w;                w += (size_t)NTOT * 16 * 8;   // bf16 emb
    ushort4* x1h  = (ushort4*)w;                w += (size_t)NTOT * 16 * 8;   // bf16 x1
    ushort4* outh = (ushort4*)w;                // bf16 aggregated node table

    const int BT = 256;
    const int HB = 3 * RNG * CHK;               // histogram blocks (384)

    // deg histograms (atomic-free) + emb bf16 convert + W-frag build, fused
    {
        int convBlocks = (NTOT * 16 + 1023) / 1024;
        deg_cvt_kernel<<<dim3(HB + convBlocks + 1), dim3(1024), 0, stream>>>(
            up_e, ut_e, utag_e, hist,
            (const float4*)up_emb, (const float4*)ut_emb, (const float4*)utag_emb,
            embh, W_src, W_dst, wfrag, NP, NT, NG, NTOT, E);
    }

    // chunk prefixes + total degree
    sumdeg_kernel<<<dim3(NB), dim3(BT), 0, stream>>>(hist, csum, deg, NTOT);

    // global parallel exclusive scan over deg (+ dinv)
    block_sums<<<dim3(NB), dim3(BT), 0, stream>>>(deg, bsum, NTOT);
    scan_bsums<<<dim3(1), dim3(1024), 0, stream>>>(bsum, NB);
    scatter_offs<<<dim3(NB), dim3(BT), 0, stream>>>(deg, bsum, offs, dinv, NTOT, 3 * E);

    // CSR build: LDS cursors from offs+csum, XCD-aligned chunk blocks
    permute3_kernel<<<dim3(CHK * 24), dim3(1024), 0, stream>>>(
        up_e, ut_e, utag_e, offs, csum, ei, NP, NT, NG, NTOT, E);

    // conv layers over ALL nodes
    int nb = ((size_t)NTOT * 16 + BT - 1) / BT;
    conv_csr1<<<dim3(nb), dim3(BT), 0, stream>>>(offs, ei, dinv, embh, x1h, NTOT);
    conv_csr2<<<dim3(nb), dim3(BT), 0, stream>>>(offs, ei, dinv, embh, x1h, outh, NTOT);

    // final v7: 16 edges per wave, MFMA feature GEMM
    {
        int blocks = (E + 63) / 64;
        final_kernel<<<dim3(blocks), dim3(BT), 0, stream>>>(
            up_e, ut_e, utag_e, src_feat, dst_feat, outh, wfrag,
            (const float4*)b_src, (const float4*)b_dst, out, E, NP, NT);
    }
}